// Round 11
// baseline (405.683 us; speedup 1.0000x reference)
//
#include <hip/hip_runtime.h>

// ---------------------------------------------------------------------------
// EMOGI ChebConv-K2 x3 : N=100000 nodes, E=800000 edges, dims 58->300->100->1
//   CSR by dst (count/scan/fill) -> gathers, no float atomics.
//   xb  [NR][128] bf16 = [x | p1 | 0]       (p1 filled by gather58)
//   k_mm12: FUSED  h1 = relu([x|p1]@W1+b1) (wave-private LDS only) ;
//           ga2b[NR][208] = h1 @ [W21|pad|W20|pad]
//   gather_l2: p2 = prop(g2); h2 = relu(a2+p2+b2) in-reg; a3,g3 = h2@W3 dots
//   gather1: out = a3 + prop(g3)
//
// R10 lesson: slab-shared W staging made the fused kernel a barrier-lockstep
// (28 syncthreads, 62.5KB LDS -> 2 blk/CU, occupancy 10%, 116us). Weights
// are L2-resident; sharing them via LDS saves bandwidth we don't need at the
// cost of latency hiding we do. Fix: ZERO barriers -- each wave loads its
// fragment-packed W directly from global (coalesced 1KB, L2-hot), LDS holds
// only the wave-private h1 stage (41KB -> 3 blk/CU), waves fully async.
// ---------------------------------------------------------------------------

typedef short bf16x8 __attribute__((ext_vector_type(8)));
typedef float f32x4 __attribute__((ext_vector_type(4)));

__device__ __forceinline__ unsigned f2bf(float f) {  // RNE fp32->bf16 bits
  unsigned u = __float_as_uint(f);
  u += 0x7fff + ((u >> 16) & 1);
  return u >> 16;
}
__device__ __forceinline__ float bf2f(unsigned s) {
  return __uint_as_float(s << 16);
}

// ---------------- CSR build ----------------
__global__ void k_count(const int* __restrict__ src, const int* __restrict__ dst,
                        unsigned* __restrict__ deg, unsigned* __restrict__ cnt, int E) {
  int i = blockIdx.x * blockDim.x + threadIdx.x;
  if (i < E) {
    atomicAdd(&deg[src[i]], 1u);
    atomicAdd(&cnt[dst[i]], 1u);
  }
}

__global__ void k_dinv(const unsigned* __restrict__ deg, float* __restrict__ dinv, int N) {
  int i = blockIdx.x * blockDim.x + threadIdx.x;
  if (i < N) {
    unsigned d = deg[i];
    dinv[i] = d ? rsqrtf((float)d) : 0.0f;
  }
}

__global__ __launch_bounds__(256) void k_scan1(const unsigned* __restrict__ cnt,
                                               unsigned* __restrict__ btot, int N) {
  __shared__ unsigned s[256];
  int b = blockIdx.x, t = threadIdx.x;
  int base = b * 1024;
  unsigned sum = 0;
  for (int i = t; i < 1024; i += 256) {
    int idx = base + i;
    sum += (idx < N) ? cnt[idx] : 0u;
  }
  s[t] = sum;
  __syncthreads();
  for (int off = 128; off > 0; off >>= 1) {
    if (t < off) s[t] += s[t + off];
    __syncthreads();
  }
  if (t == 0) btot[b] = s[0];
}

__global__ __launch_bounds__(256) void k_scan2(unsigned* __restrict__ btot,
                                               unsigned* __restrict__ rowstart,
                                               int NB, int N, int E) {
  __shared__ unsigned s[256];
  int t = threadIdx.x;
  s[t] = (t < NB) ? btot[t] : 0u;
  __syncthreads();
  if (t == 0) {
    unsigned acc = 0;
    for (int i = 0; i < NB; i++) { unsigned v = s[i]; s[i] = acc; acc += v; }
  }
  __syncthreads();
  if (t < NB) btot[t] = s[t];
  if (t == 0) rowstart[N] = (unsigned)E;
}

__global__ __launch_bounds__(256) void k_scan3(const unsigned* __restrict__ cnt,
                                               const unsigned* __restrict__ btot,
                                               unsigned* __restrict__ rowstart,
                                               unsigned* __restrict__ cursor, int N) {
  __shared__ unsigned ssum[256];
  int b = blockIdx.x, t = threadIdx.x;
  int base = b * 1024 + t * 4;
  unsigned v0 = 0, v1 = 0, v2 = 0, v3 = 0;
  if (base + 0 < N) v0 = cnt[base + 0];
  if (base + 1 < N) v1 = cnt[base + 1];
  if (base + 2 < N) v2 = cnt[base + 2];
  if (base + 3 < N) v3 = cnt[base + 3];
  ssum[t] = v0 + v1 + v2 + v3;
  __syncthreads();
  for (int off = 1; off < 256; off <<= 1) {
    unsigned add = (t >= off) ? ssum[t - off] : 0u;
    __syncthreads();
    ssum[t] += add;
    __syncthreads();
  }
  unsigned texcl = ((t == 0) ? 0u : ssum[t - 1]) + btot[b];
  unsigned r0 = texcl, r1 = r0 + v0, r2 = r1 + v1, r3 = r2 + v2;
  if (base + 0 < N) { rowstart[base + 0] = r0; cursor[base + 0] = r0; }
  if (base + 1 < N) { rowstart[base + 1] = r1; cursor[base + 1] = r1; }
  if (base + 2 < N) { rowstart[base + 2] = r2; cursor[base + 2] = r2; }
  if (base + 3 < N) { rowstart[base + 3] = r3; cursor[base + 3] = r3; }
}

__global__ void k_fill(const int* __restrict__ src, const int* __restrict__ dst,
                       const float* __restrict__ dinv, unsigned* __restrict__ cursor,
                       int2* __restrict__ er, int E) {
  int e = blockIdx.x * blockDim.x + threadIdx.x;
  if (e >= E) return;
  int s = src[e], d = dst[e];
  unsigned pos = atomicAdd(&cursor[d], 1u);
  er[pos] = make_int2(s, __float_as_int(dinv[s]));
}

// ---------------- prep kernels ----------------
__global__ void k_prep_xb(const float* __restrict__ x, unsigned short* __restrict__ xb, int N) {
  int idx = blockIdx.x * blockDim.x + threadIdx.x;
  int n = idx >> 6, p = idx & 63;
  if (n >= N) return;
  int c = p * 2;
  if (c < 58) {
    unsigned lo = f2bf(x[(size_t)n * 58 + c]);
    unsigned hi = f2bf(x[(size_t)n * 58 + c + 1]);
    *(unsigned*)(xb + (size_t)n * 128 + c) = lo | (hi << 16);
  } else if (c >= 116) {
    *(unsigned*)(xb + (size_t)n * 128 + c) = 0;
  }
}

// W1f fragment-packed [s<4][j<20][lane<64][8 bf16]:
// value = W1cat[k = s*32+(lane>>4)*8+i][c = j*16+(lane&15)]; 0 outside.
__global__ void k_prep_w1f(const float* __restrict__ W1, uint4* __restrict__ W1f) {
  int idx = blockIdx.x * blockDim.x + threadIdx.x;
  if (idx >= 4 * 20 * 64) return;
  int lane = idx & 63, j = (idx >> 6) % 20, s = (idx >> 6) / 20;
  int lr = lane & 15, g = lane >> 4;
  int c = j * 16 + lr;
  unsigned short v[8];
#pragma unroll
  for (int i = 0; i < 8; i++) {
    int k = s * 32 + g * 8 + i;
    float f = 0.0f;
    if (c < 300 && k < 116)
      f = (k < 58) ? W1[k * 300 + c] : W1[17400 + (k - 58) * 300 + c];
    v[i] = (unsigned short)f2bf(f);
  }
  W1f[idx] = *(const uint4*)v;
}

// W2f fragment-packed [s<10][j<13][lane<64][8 bf16]:
// rows r=j*16+lr: r<100 -> W21[k][r] (g2) ; 104<=r<204 -> W20[k][r-104] (a2).
__global__ void k_prep_w2f(const float* __restrict__ W2, uint4* __restrict__ W2f) {
  int idx = blockIdx.x * blockDim.x + threadIdx.x;
  if (idx >= 10 * 13 * 64) return;
  int lane = idx & 63, j = (idx >> 6) % 13, s = (idx >> 6) / 13;
  int lr = lane & 15, g = lane >> 4;
  int r = j * 16 + lr;
  unsigned short v[8];
#pragma unroll
  for (int i = 0; i < 8; i++) {
    int k = s * 32 + g * 8 + i;
    float f = 0.0f;
    if (k < 300) {
      if (r < 100) f = W2[30000 + k * 100 + r];
      else if (r >= 104 && r < 204) f = W2[k * 100 + (r - 104)];
    }
    v[i] = (unsigned short)f2bf(f);
  }
  W2f[idx] = *(const uint4*)v;
}

__global__ void k_prep_b1pad(const float* __restrict__ b1, float* __restrict__ b1pad) {
  int t = blockIdx.x * blockDim.x + threadIdx.x;
  if (t < 320) b1pad[t] = (t < 300) ? b1[t] : 0.0f;
}

// ---------------- gathers (x4 MLP-unrolled) ----------------
__global__ __launch_bounds__(256) void k_gather58(
    const unsigned* __restrict__ rowstart, const int2* __restrict__ er,
    const float* __restrict__ dinv, unsigned short* __restrict__ xb, int N) {
  int wid = (blockIdx.x * blockDim.x + threadIdx.x) >> 6;
  if (wid >= N) return;
  int lane = threadIdx.x & 63;
  int c0 = lane * 2;
  if (c0 >= 58) return;
  unsigned s0 = rowstart[wid], s1 = rowstart[wid + 1];
  float a0 = 0.f, a1 = 0.f, b0 = 0.f, b1 = 0.f;
  float c0a = 0.f, c1a = 0.f, d0 = 0.f, d1 = 0.f;
  unsigned e = s0;
  for (; e + 4 <= s1; e += 4) {
    int2 r0 = er[e], r1 = er[e + 1], r2 = er[e + 2], r3 = er[e + 3];
    unsigned v0 = *(const unsigned*)(xb + (size_t)r0.x * 128 + c0);
    unsigned v1 = *(const unsigned*)(xb + (size_t)r1.x * 128 + c0);
    unsigned v2 = *(const unsigned*)(xb + (size_t)r2.x * 128 + c0);
    unsigned v3 = *(const unsigned*)(xb + (size_t)r3.x * 128 + c0);
    float w0 = __int_as_float(r0.y), w1 = __int_as_float(r1.y);
    float w2 = __int_as_float(r2.y), w3 = __int_as_float(r3.y);
    a0 += w0 * bf2f(v0 & 0xffffu); a1 += w0 * bf2f(v0 >> 16);
    b0 += w1 * bf2f(v1 & 0xffffu); b1 += w1 * bf2f(v1 >> 16);
    c0a += w2 * bf2f(v2 & 0xffffu); c1a += w2 * bf2f(v2 >> 16);
    d0 += w3 * bf2f(v3 & 0xffffu); d1 += w3 * bf2f(v3 >> 16);
  }
  for (; e < s1; ++e) {
    int2 r = er[e];
    float w = __int_as_float(r.y);
    unsigned v = *(const unsigned*)(xb + (size_t)r.x * 128 + c0);
    a0 += w * bf2f(v & 0xffffu); a1 += w * bf2f(v >> 16);
  }
  float dd = -dinv[wid];
  float p0 = dd * ((a0 + b0) + (c0a + d0));
  float p1 = dd * ((a1 + b1) + (c1a + d1));
  *(unsigned*)(xb + (size_t)wid * 128 + 58 + c0) = f2bf(p0) | (f2bf(p1) << 16);
}

// layer2 tail fused: p2 = prop(g2); h2 = relu(a2+p2+b2); a3,g3 = h2@W30/W31
__global__ __launch_bounds__(256) void k_gather_l2(
    const unsigned* __restrict__ rowstart, const int2* __restrict__ er,
    const float* __restrict__ dinv, const unsigned short* __restrict__ ga2b,
    const float* __restrict__ b2, const float* __restrict__ W30,
    const float* __restrict__ W31, const float* __restrict__ b3,
    float* __restrict__ a3, float* __restrict__ g3, int N) {
  int wid = (blockIdx.x * blockDim.x + threadIdx.x) >> 6;
  if (wid >= N) return;
  int lane = threadIdx.x & 63;
  int c0 = lane * 2;
  bool act = c0 < 100;
  unsigned s0 = rowstart[wid], s1 = rowstart[wid + 1];
  float aa = 0.f, gg = 0.f;
  if (act) {
    float a0 = 0.f, a1 = 0.f, b0 = 0.f, b1 = 0.f;
    float c0a = 0.f, c1a = 0.f, d0 = 0.f, d1 = 0.f;
    unsigned e = s0;
    for (; e + 4 <= s1; e += 4) {
      int2 r0 = er[e], r1 = er[e + 1], r2 = er[e + 2], r3 = er[e + 3];
      unsigned v0 = *(const unsigned*)(ga2b + (size_t)r0.x * 208 + c0);
      unsigned v1 = *(const unsigned*)(ga2b + (size_t)r1.x * 208 + c0);
      unsigned v2 = *(const unsigned*)(ga2b + (size_t)r2.x * 208 + c0);
      unsigned v3 = *(const unsigned*)(ga2b + (size_t)r3.x * 208 + c0);
      float w0 = __int_as_float(r0.y), w1 = __int_as_float(r1.y);
      float w2 = __int_as_float(r2.y), w3 = __int_as_float(r3.y);
      a0 += w0 * bf2f(v0 & 0xffffu); a1 += w0 * bf2f(v0 >> 16);
      b0 += w1 * bf2f(v1 & 0xffffu); b1 += w1 * bf2f(v1 >> 16);
      c0a += w2 * bf2f(v2 & 0xffffu); c1a += w2 * bf2f(v2 >> 16);
      d0 += w3 * bf2f(v3 & 0xffffu); d1 += w3 * bf2f(v3 >> 16);
    }
    for (; e < s1; ++e) {
      int2 r = er[e];
      float w = __int_as_float(r.y);
      unsigned v = *(const unsigned*)(ga2b + (size_t)r.x * 208 + c0);
      a0 += w * bf2f(v & 0xffffu); a1 += w * bf2f(v >> 16);
    }
    float dd = -dinv[wid];
    float p0 = dd * ((a0 + b0) + (c0a + d0));
    float p1 = dd * ((a1 + b1) + (c1a + d1));
    unsigned av = *(const unsigned*)(ga2b + (size_t)wid * 208 + 104 + c0);
    float h0 = fmaxf(bf2f(av & 0xffffu) + p0 + b2[c0], 0.f);
    float h1 = fmaxf(bf2f(av >> 16) + p1 + b2[c0 + 1], 0.f);
    aa = h0 * W30[c0] + h1 * W30[c0 + 1];
    gg = h0 * W31[c0] + h1 * W31[c0 + 1];
  }
#pragma unroll
  for (int off = 32; off > 0; off >>= 1) {
    aa += __shfl_xor(aa, off);
    gg += __shfl_xor(gg, off);
  }
  if (lane == 0) {
    a3[wid] = aa + b3[0];
    g3[wid] = gg;
  }
}

__global__ void k_gather1(const unsigned* __restrict__ rowstart, const int2* __restrict__ er,
                          const float* __restrict__ dinv, const float* __restrict__ g3,
                          const float* __restrict__ a3, float* __restrict__ out, int N) {
  int n = blockIdx.x * blockDim.x + threadIdx.x;
  if (n >= N) return;
  unsigned s0 = rowstart[n], s1 = rowstart[n + 1];
  float a = 0.f, b = 0.f, c = 0.f, d = 0.f;
  unsigned e = s0;
  for (; e + 4 <= s1; e += 4) {
    int2 r0 = er[e], r1 = er[e + 1], r2 = er[e + 2], r3 = er[e + 3];
    float g0 = g3[r0.x], g1 = g3[r1.x], g2v = g3[r2.x], g3v = g3[r3.x];
    a += __int_as_float(r0.y) * g0;
    b += __int_as_float(r1.y) * g1;
    c += __int_as_float(r2.y) * g2v;
    d += __int_as_float(r3.y) * g3v;
  }
  for (; e < s1; ++e) {
    int2 r = er[e];
    a += __int_as_float(r.y) * g3[r.x];
  }
  out[n] = a3[n] - dinv[n] * ((a + b) + (c + d));
}

// ---------------- FUSED MFMA layer1+layer2 (no barriers) ----------------
// Per wave (16 nodes), fully independent -- no __syncthreads anywhere:
//   mm1: 4 s-steps, W frags DIRECT from global (coalesced 1KB, L2-hot):
//        acc1[j] += mfma(W1f[s][j], a_xb[s])
//   h1 epilogue: relu+bias -> bf16 wave-private LDS stage [16][328]
//   mm2: 10 s-steps: A-frag = ds_read stage; acc2[j] += mfma(W2f[s][j], a)
//   out: reuse stage as [16][216], copy 6656B contiguous per wave.
#define STG 328  // stage row stride (elements)
__global__ __launch_bounds__(256, 3) void k_mm12_mfma(
    const unsigned short* __restrict__ xb, const uint4* __restrict__ W1f,
    const uint4* __restrict__ W2f, const float* __restrict__ b1pad,
    unsigned short* __restrict__ ga2b) {
  __shared__ unsigned short stage[4 * 16 * STG];  // 41 KB, wave-private slices
  int tid = threadIdx.x;
  int lane = tid & 63, wv = tid >> 6, lr = lane & 15, g = lane >> 4;
  int n0 = blockIdx.x * 64 + wv * 16;
  unsigned short* ost = stage + wv * 16 * STG;

  // ---- mm1: direct-global W, per-wave async ----
  f32x4 acc1[20];
#pragma unroll
  for (int j = 0; j < 20; j++) acc1[j] = (f32x4){0.f, 0.f, 0.f, 0.f};
#pragma unroll
  for (int s = 0; s < 4; s++) {
    bf16x8 a = *(const bf16x8*)(xb + (size_t)(n0 + lr) * 128 + s * 32 + g * 8);
#pragma unroll
    for (int j = 0; j < 20; j++) {
      bf16x8 w = *(const bf16x8*)&W1f[(s * 20 + j) * 64 + lane];
      acc1[j] = __builtin_amdgcn_mfma_f32_16x16x32_bf16(w, a, acc1[j], 0, 0, 0);
    }
  }
  // h1 -> wave-private stage (bf16). cols 300..319 are 0 (zero W pad + bias).
#pragma unroll
  for (int j = 0; j < 20; j++) {
    float4 bv = *(const float4*)(b1pad + j * 16 + g * 4);
    unsigned lo = f2bf(fmaxf(acc1[j][0] + bv.x, 0.f)) |
                  (f2bf(fmaxf(acc1[j][1] + bv.y, 0.f)) << 16);
    unsigned hi = f2bf(fmaxf(acc1[j][2] + bv.z, 0.f)) |
                  (f2bf(fmaxf(acc1[j][3] + bv.w, 0.f)) << 16);
    uint2 pk; pk.x = lo; pk.y = hi;
    *(uint2*)(ost + lr * STG + j * 16 + g * 4) = pk;
  }

  // ---- mm2: A from wave-private stage, W direct from global ----
  f32x4 acc2[13];
#pragma unroll
  for (int j = 0; j < 13; j++) acc2[j] = (f32x4){0.f, 0.f, 0.f, 0.f};
#pragma unroll
  for (int s = 0; s < 10; s++) {
    bf16x8 a = *(const bf16x8*)(ost + lr * STG + s * 32 + g * 8);
#pragma unroll
    for (int j = 0; j < 13; j++) {
      bf16x8 w = *(const bf16x8*)&W2f[(s * 13 + j) * 64 + lane];
      acc2[j] = __builtin_amdgcn_mfma_f32_16x16x32_bf16(w, a, acc2[j], 0, 0, 0);
    }
  }
  // out epilogue: reuse wave-private stage as [16][216]; same-wave LDS order
  // guarantees all h1 reads retired before these writes.
#pragma unroll
  for (int j = 0; j < 13; j++) {
    unsigned lo = f2bf(acc2[j][0]) | (f2bf(acc2[j][1]) << 16);
    unsigned hi = f2bf(acc2[j][2]) | (f2bf(acc2[j][3]) << 16);
    uint2 pk; pk.x = lo; pk.y = hi;
    *(uint2*)(ost + lr * 216 + j * 16 + g * 4) = pk;
  }
  // wave tile rows n0..n0+15 x 208 cols = 6656 contiguous bytes
  uint4* gdst = (uint4*)(ga2b + (size_t)n0 * 208);
  for (int idx = lane; idx < 416; idx += 64) {
    int row = idx / 26, q = idx - row * 26;
    gdst[idx] = *(const uint4*)(ost + row * 216 + q * 8);
  }
}

// ---------------- launch ----------------
extern "C" void kernel_launch(void* const* d_in, const int* in_sizes, int n_in,
                              void* d_out, int out_size, void* d_ws, size_t ws_size,
                              hipStream_t stream) {
  const float* x  = (const float*)d_in[0];
  const int*   ei = (const int*)d_in[1];
  const float* W1 = (const float*)d_in[2];  // [2][58][300]
  const float* b1 = (const float*)d_in[3];
  const float* W2 = (const float*)d_in[4];  // [2][300][100]
  const float* b2 = (const float*)d_in[5];
  const float* W3 = (const float*)d_in[6];  // [2][100][1]
  const float* b3 = (const float*)d_in[7];
  float* out = (float*)d_out;

  const int N = in_sizes[0] / 58;            // 100000
  const int E = in_sizes[1] / 2;             // 800000
  const int NR = (N + 127) & ~127;           // 100096 (multiple of 64)
  const int NB = (N + 1023) / 1024;
  const int* src = ei;
  const int* dst = ei + E;

  char* ws = (char*)d_ws;
  size_t off = 0;
  auto alloc = [&](size_t bytes) -> void* {
    void* p = ws + off;
    off += (bytes + 255) & ~(size_t)255;
    return p;
  };
  unsigned* deg      = (unsigned*)alloc((size_t)2 * N * 4);
  unsigned* cnt      = deg + N;
  float*    dinv     = (float*)alloc((size_t)N * 4);
  unsigned* rowstart = (unsigned*)alloc((size_t)(N + 1) * 4);
  unsigned* cursor   = (unsigned*)alloc((size_t)N * 4);
  unsigned* btot     = (unsigned*)alloc((size_t)256 * 4);
  int2*     er       = (int2*)alloc((size_t)E * 8);
  unsigned short* xb   = (unsigned short*)alloc((size_t)NR * 128 * 2);
  uint4*    W1f      = (uint4*)alloc((size_t)4 * 20 * 64 * 16);   // 80 KB
  uint4*    W2f      = (uint4*)alloc((size_t)10 * 13 * 64 * 16);  // 133 KB
  float*    b1pad    = (float*)alloc((size_t)320 * 4);
  unsigned short* ga2b = (unsigned short*)alloc((size_t)NR * 208 * 2);
  float* a3 = (float*)alloc((size_t)N * 4);
  float* g3 = (float*)alloc((size_t)N * 4);

  // --- CSR + dinv ---
  hipMemsetAsync(deg, 0, (size_t)2 * N * 4, stream);
  k_count<<<(E + 255) / 256, 256, 0, stream>>>(src, dst, deg, cnt, E);
  k_dinv<<<(N + 255) / 256, 256, 0, stream>>>(deg, dinv, N);
  k_scan1<<<NB, 256, 0, stream>>>(cnt, btot, N);
  k_scan2<<<1, 256, 0, stream>>>(btot, rowstart, NB, N, E);
  k_scan3<<<NB, 256, 0, stream>>>(cnt, btot, rowstart, cursor, N);
  k_fill<<<(E + 255) / 256, 256, 0, stream>>>(src, dst, dinv, cursor, er, E);

  // --- preps ---
  k_prep_w1f<<<(4 * 20 * 64 + 255) / 256, 256, 0, stream>>>(W1, W1f);
  k_prep_w2f<<<(10 * 13 * 64 + 255) / 256, 256, 0, stream>>>(W2, W2f);
  k_prep_b1pad<<<2, 256, 0, stream>>>(b1, b1pad);
  k_prep_xb<<<((size_t)N * 64 + 255) / 256, 256, 0, stream>>>(x, xb, N);

  // --- layer 1+2 fused ---
  k_gather58<<<(N + 3) / 4, 256, 0, stream>>>(rowstart, er, dinv, xb, N);
  k_mm12_mfma<<<NR / 64, 256, 0, stream>>>(xb, W1f, W2f, b1pad, ga2b);
  k_gather_l2<<<(N + 3) / 4, 256, 0, stream>>>(rowstart, er, dinv, ga2b,
                                               b2, W3, W3 + 100, b3, a3, g3, N);

  // --- layer 3 ---
  k_gather1<<<(N + 255) / 256, 256, 0, stream>>>(rowstart, er, dinv, g3, a3, out, N);
}

// Round 12
// 347.894 us; speedup vs baseline: 1.1661x; 1.1661x over previous
//
#include <hip/hip_runtime.h>

// ---------------------------------------------------------------------------
// EMOGI ChebConv-K2 x3 : N=100000 nodes, E=800000 edges, dims 58->300->100->1
//   CSR by dst (count+rank / scan / fill-no-atomic) -> gathers.
//   xb  [NR][128] bf16 = [x | p1 | 0]       (p1 filled by gather58)
//   k_mm12: FUSED  h1 = relu([x|p1]@W1+b1) (wave-private LDS stage) ;
//           ga2b[NR][208] = h1 @ [W21|pad|W20|pad]
//   gather_l2: p2 = prop(g2); h2 = relu(a2+p2+b2) in-reg; a3,g3 = h2@W3 dots
//   gather1: out = a3 + prop(g3)
//
// R11 lesson: EVERY mm variant ran 65-140us at MfmaUtil ~6% because the
// inner loop was "w=load; acc=mfma(w,..)" -- compiler (VGPR=84) holds 1-2
// W frags in flight -> one ~300cyc L2 trip PER MFMA (10s x 13j x 300 = 39K
// cyc/wave = the whole kernel time). Fix: explicit fragment ARRAYS
// (load w[13] loop, then mfma loop) -- dataflow forces all loads in flight,
// one latency covers 13. Stage stride 324 (bank step 2 -> conflict-free
// writes). fill atomic merged into count via per-edge rank.
// ---------------------------------------------------------------------------

typedef short bf16x8 __attribute__((ext_vector_type(8)));
typedef float f32x4 __attribute__((ext_vector_type(4)));

__device__ __forceinline__ unsigned f2bf(float f) {  // RNE fp32->bf16 bits
  unsigned u = __float_as_uint(f);
  u += 0x7fff + ((u >> 16) & 1);
  return u >> 16;
}
__device__ __forceinline__ float bf2f(unsigned s) {
  return __uint_as_float(s << 16);
}

// ---------------- CSR build ----------------
__global__ void k_count(const int* __restrict__ src, const int* __restrict__ dst,
                        unsigned* __restrict__ deg, unsigned* __restrict__ cnt,
                        unsigned* __restrict__ rank, int E) {
  int i = blockIdx.x * blockDim.x + threadIdx.x;
  if (i < E) {
    atomicAdd(&deg[src[i]], 1u);
    rank[i] = atomicAdd(&cnt[dst[i]], 1u);
  }
}

__global__ void k_dinv(const unsigned* __restrict__ deg, float* __restrict__ dinv, int N) {
  int i = blockIdx.x * blockDim.x + threadIdx.x;
  if (i < N) {
    unsigned d = deg[i];
    dinv[i] = d ? rsqrtf((float)d) : 0.0f;
  }
}

__global__ __launch_bounds__(256) void k_scan1(const unsigned* __restrict__ cnt,
                                               unsigned* __restrict__ btot, int N) {
  __shared__ unsigned s[256];
  int b = blockIdx.x, t = threadIdx.x;
  int base = b * 1024;
  unsigned sum = 0;
  for (int i = t; i < 1024; i += 256) {
    int idx = base + i;
    sum += (idx < N) ? cnt[idx] : 0u;
  }
  s[t] = sum;
  __syncthreads();
  for (int off = 128; off > 0; off >>= 1) {
    if (t < off) s[t] += s[t + off];
    __syncthreads();
  }
  if (t == 0) btot[b] = s[0];
}

__global__ __launch_bounds__(256) void k_scan2(unsigned* __restrict__ btot,
                                               unsigned* __restrict__ rowstart,
                                               int NB, int N, int E) {
  __shared__ unsigned s[256];
  int t = threadIdx.x;
  s[t] = (t < NB) ? btot[t] : 0u;
  __syncthreads();
  if (t == 0) {
    unsigned acc = 0;
    for (int i = 0; i < NB; i++) { unsigned v = s[i]; s[i] = acc; acc += v; }
  }
  __syncthreads();
  if (t < NB) btot[t] = s[t];
  if (t == 0) rowstart[N] = (unsigned)E;
}

__global__ __launch_bounds__(256) void k_scan3(const unsigned* __restrict__ cnt,
                                               const unsigned* __restrict__ btot,
                                               unsigned* __restrict__ rowstart, int N) {
  __shared__ unsigned ssum[256];
  int b = blockIdx.x, t = threadIdx.x;
  int base = b * 1024 + t * 4;
  unsigned v0 = 0, v1 = 0, v2 = 0, v3 = 0;
  if (base + 0 < N) v0 = cnt[base + 0];
  if (base + 1 < N) v1 = cnt[base + 1];
  if (base + 2 < N) v2 = cnt[base + 2];
  if (base + 3 < N) v3 = cnt[base + 3];
  ssum[t] = v0 + v1 + v2 + v3;
  __syncthreads();
  for (int off = 1; off < 256; off <<= 1) {
    unsigned add = (t >= off) ? ssum[t - off] : 0u;
    __syncthreads();
    ssum[t] += add;
    __syncthreads();
  }
  unsigned texcl = ((t == 0) ? 0u : ssum[t - 1]) + btot[b];
  unsigned r0 = texcl, r1 = r0 + v0, r2 = r1 + v1, r3 = r2 + v2;
  if (base + 0 < N) rowstart[base + 0] = r0;
  if (base + 1 < N) rowstart[base + 1] = r1;
  if (base + 2 < N) rowstart[base + 2] = r2;
  if (base + 3 < N) rowstart[base + 3] = r3;
}

// fill without atomics: position = rowstart[dst] + rank (from k_count)
__global__ void k_fill(const int* __restrict__ src, const int* __restrict__ dst,
                       const float* __restrict__ dinv, const unsigned* __restrict__ rowstart,
                       const unsigned* __restrict__ rank, int2* __restrict__ er, int E) {
  int e = blockIdx.x * blockDim.x + threadIdx.x;
  if (e >= E) return;
  int s = src[e], d = dst[e];
  er[rowstart[d] + rank[e]] = make_int2(s, __float_as_int(dinv[s]));
}

// ---------------- prep kernels ----------------
__global__ void k_prep_xb(const float* __restrict__ x, unsigned short* __restrict__ xb, int N) {
  int idx = blockIdx.x * blockDim.x + threadIdx.x;
  int n = idx >> 6, p = idx & 63;
  if (n >= N) return;
  int c = p * 2;
  if (c < 58) {
    unsigned lo = f2bf(x[(size_t)n * 58 + c]);
    unsigned hi = f2bf(x[(size_t)n * 58 + c + 1]);
    *(unsigned*)(xb + (size_t)n * 128 + c) = lo | (hi << 16);
  } else if (c >= 116) {
    *(unsigned*)(xb + (size_t)n * 128 + c) = 0;
  }
}

// W1f fragment-packed [s<4][j<20][lane<64][8 bf16]
__global__ void k_prep_w1f(const float* __restrict__ W1, uint4* __restrict__ W1f) {
  int idx = blockIdx.x * blockDim.x + threadIdx.x;
  if (idx >= 4 * 20 * 64) return;
  int lane = idx & 63, j = (idx >> 6) % 20, s = (idx >> 6) / 20;
  int lr = lane & 15, g = lane >> 4;
  int c = j * 16 + lr;
  unsigned short v[8];
#pragma unroll
  for (int i = 0; i < 8; i++) {
    int k = s * 32 + g * 8 + i;
    float f = 0.0f;
    if (c < 300 && k < 116)
      f = (k < 58) ? W1[k * 300 + c] : W1[17400 + (k - 58) * 300 + c];
    v[i] = (unsigned short)f2bf(f);
  }
  W1f[idx] = *(const uint4*)v;
}

// W2f fragment-packed [s<10][j<13][lane<64][8 bf16]
__global__ void k_prep_w2f(const float* __restrict__ W2, uint4* __restrict__ W2f) {
  int idx = blockIdx.x * blockDim.x + threadIdx.x;
  if (idx >= 10 * 13 * 64) return;
  int lane = idx & 63, j = (idx >> 6) % 13, s = (idx >> 6) / 13;
  int lr = lane & 15, g = lane >> 4;
  int r = j * 16 + lr;
  unsigned short v[8];
#pragma unroll
  for (int i = 0; i < 8; i++) {
    int k = s * 32 + g * 8 + i;
    float f = 0.0f;
    if (k < 300) {
      if (r < 100) f = W2[30000 + k * 100 + r];
      else if (r >= 104 && r < 204) f = W2[k * 100 + (r - 104)];
    }
    v[i] = (unsigned short)f2bf(f);
  }
  W2f[idx] = *(const uint4*)v;
}

__global__ void k_prep_b1pad(const float* __restrict__ b1, float* __restrict__ b1pad) {
  int t = blockIdx.x * blockDim.x + threadIdx.x;
  if (t < 320) b1pad[t] = (t < 300) ? b1[t] : 0.0f;
}

// ---------------- gathers (x4 MLP-unrolled) ----------------
__global__ __launch_bounds__(256) void k_gather58(
    const unsigned* __restrict__ rowstart, const int2* __restrict__ er,
    const float* __restrict__ dinv, unsigned short* __restrict__ xb, int N) {
  int wid = (blockIdx.x * blockDim.x + threadIdx.x) >> 6;
  if (wid >= N) return;
  int lane = threadIdx.x & 63;
  int c0 = lane * 2;
  if (c0 >= 58) return;
  unsigned s0 = rowstart[wid], s1 = rowstart[wid + 1];
  float a0 = 0.f, a1 = 0.f, b0 = 0.f, b1 = 0.f;
  float c0a = 0.f, c1a = 0.f, d0 = 0.f, d1 = 0.f;
  unsigned e = s0;
  for (; e + 4 <= s1; e += 4) {
    int2 r0 = er[e], r1 = er[e + 1], r2 = er[e + 2], r3 = er[e + 3];
    unsigned v0 = *(const unsigned*)(xb + (size_t)r0.x * 128 + c0);
    unsigned v1 = *(const unsigned*)(xb + (size_t)r1.x * 128 + c0);
    unsigned v2 = *(const unsigned*)(xb + (size_t)r2.x * 128 + c0);
    unsigned v3 = *(const unsigned*)(xb + (size_t)r3.x * 128 + c0);
    float w0 = __int_as_float(r0.y), w1 = __int_as_float(r1.y);
    float w2 = __int_as_float(r2.y), w3 = __int_as_float(r3.y);
    a0 += w0 * bf2f(v0 & 0xffffu); a1 += w0 * bf2f(v0 >> 16);
    b0 += w1 * bf2f(v1 & 0xffffu); b1 += w1 * bf2f(v1 >> 16);
    c0a += w2 * bf2f(v2 & 0xffffu); c1a += w2 * bf2f(v2 >> 16);
    d0 += w3 * bf2f(v3 & 0xffffu); d1 += w3 * bf2f(v3 >> 16);
  }
  for (; e < s1; ++e) {
    int2 r = er[e];
    float w = __int_as_float(r.y);
    unsigned v = *(const unsigned*)(xb + (size_t)r.x * 128 + c0);
    a0 += w * bf2f(v & 0xffffu); a1 += w * bf2f(v >> 16);
  }
  float dd = -dinv[wid];
  float p0 = dd * ((a0 + b0) + (c0a + d0));
  float p1 = dd * ((a1 + b1) + (c1a + d1));
  *(unsigned*)(xb + (size_t)wid * 128 + 58 + c0) = f2bf(p0) | (f2bf(p1) << 16);
}

// layer2 tail fused: p2 = prop(g2); h2 = relu(a2+p2+b2); a3,g3 = h2@W30/W31
__global__ __launch_bounds__(256) void k_gather_l2(
    const unsigned* __restrict__ rowstart, const int2* __restrict__ er,
    const float* __restrict__ dinv, const unsigned short* __restrict__ ga2b,
    const float* __restrict__ b2, const float* __restrict__ W30,
    const float* __restrict__ W31, const float* __restrict__ b3,
    float* __restrict__ a3, float* __restrict__ g3, int N) {
  int wid = (blockIdx.x * blockDim.x + threadIdx.x) >> 6;
  if (wid >= N) return;
  int lane = threadIdx.x & 63;
  int c0 = lane * 2;
  bool act = c0 < 100;
  unsigned s0 = rowstart[wid], s1 = rowstart[wid + 1];
  float aa = 0.f, gg = 0.f;
  if (act) {
    float a0 = 0.f, a1 = 0.f, b0 = 0.f, b1 = 0.f;
    float c0a = 0.f, c1a = 0.f, d0 = 0.f, d1 = 0.f;
    unsigned e = s0;
    for (; e + 4 <= s1; e += 4) {
      int2 r0 = er[e], r1 = er[e + 1], r2 = er[e + 2], r3 = er[e + 3];
      unsigned v0 = *(const unsigned*)(ga2b + (size_t)r0.x * 208 + c0);
      unsigned v1 = *(const unsigned*)(ga2b + (size_t)r1.x * 208 + c0);
      unsigned v2 = *(const unsigned*)(ga2b + (size_t)r2.x * 208 + c0);
      unsigned v3 = *(const unsigned*)(ga2b + (size_t)r3.x * 208 + c0);
      float w0 = __int_as_float(r0.y), w1 = __int_as_float(r1.y);
      float w2 = __int_as_float(r2.y), w3 = __int_as_float(r3.y);
      a0 += w0 * bf2f(v0 & 0xffffu); a1 += w0 * bf2f(v0 >> 16);
      b0 += w1 * bf2f(v1 & 0xffffu); b1 += w1 * bf2f(v1 >> 16);
      c0a += w2 * bf2f(v2 & 0xffffu); c1a += w2 * bf2f(v2 >> 16);
      d0 += w3 * bf2f(v3 & 0xffffu); d1 += w3 * bf2f(v3 >> 16);
    }
    for (; e < s1; ++e) {
      int2 r = er[e];
      float w = __int_as_float(r.y);
      unsigned v = *(const unsigned*)(ga2b + (size_t)r.x * 208 + c0);
      a0 += w * bf2f(v & 0xffffu); a1 += w * bf2f(v >> 16);
    }
    float dd = -dinv[wid];
    float p0 = dd * ((a0 + b0) + (c0a + d0));
    float p1 = dd * ((a1 + b1) + (c1a + d1));
    unsigned av = *(const unsigned*)(ga2b + (size_t)wid * 208 + 104 + c0);
    float h0 = fmaxf(bf2f(av & 0xffffu) + p0 + b2[c0], 0.f);
    float h1 = fmaxf(bf2f(av >> 16) + p1 + b2[c0 + 1], 0.f);
    aa = h0 * W30[c0] + h1 * W30[c0 + 1];
    gg = h0 * W31[c0] + h1 * W31[c0 + 1];
  }
#pragma unroll
  for (int off = 32; off > 0; off >>= 1) {
    aa += __shfl_xor(aa, off);
    gg += __shfl_xor(gg, off);
  }
  if (lane == 0) {
    a3[wid] = aa + b3[0];
    g3[wid] = gg;
  }
}

__global__ void k_gather1(const unsigned* __restrict__ rowstart, const int2* __restrict__ er,
                          const float* __restrict__ dinv, const float* __restrict__ g3,
                          const float* __restrict__ a3, float* __restrict__ out, int N) {
  int n = blockIdx.x * blockDim.x + threadIdx.x;
  if (n >= N) return;
  unsigned s0 = rowstart[n], s1 = rowstart[n + 1];
  float a = 0.f, b = 0.f, c = 0.f, d = 0.f;
  unsigned e = s0;
  for (; e + 4 <= s1; e += 4) {
    int2 r0 = er[e], r1 = er[e + 1], r2 = er[e + 2], r3 = er[e + 3];
    float g0 = g3[r0.x], g1 = g3[r1.x], g2v = g3[r2.x], g3v = g3[r3.x];
    a += __int_as_float(r0.y) * g0;
    b += __int_as_float(r1.y) * g1;
    c += __int_as_float(r2.y) * g2v;
    d += __int_as_float(r3.y) * g3v;
  }
  for (; e < s1; ++e) {
    int2 r = er[e];
    a += __int_as_float(r.y) * g3[r.x];
  }
  out[n] = a3[n] - dinv[n] * ((a + b) + (c + d));
}

// ---------------- FUSED MFMA layer1+layer2 (no barriers, grouped loads) -----
// Per wave (16 nodes), independent. The critical structure: W fragments are
// loaded into explicit ARRAYS first, then consumed -- dataflow forces 10-13
// loads in flight so ONE L2 latency covers the group (R11 had load->mfma
// pairs = one 300cyc stall per MFMA).
#define STG 324  // 648B row stride: bank step 2 -> 16 rows on 16 even banks
__global__ __launch_bounds__(256, 3) void k_mm12_mfma(
    const unsigned short* __restrict__ xb, const uint4* __restrict__ W1f,
    const uint4* __restrict__ W2f, const float* __restrict__ b1pad,
    unsigned short* __restrict__ ga2b) {
  __shared__ unsigned short stage[4 * 16 * STG];  // 41.5 KB -> 3 blk/CU
  int tid = threadIdx.x;
  int lane = tid & 63, wv = tid >> 6, lr = lane & 15, g = lane >> 4;
  int n0 = blockIdx.x * 64 + wv * 16;
  unsigned short* ost = stage + wv * 16 * STG;

  // ---- mm1 ----
  f32x4 acc1[20];
#pragma unroll
  for (int j = 0; j < 20; j++) acc1[j] = (f32x4){0.f, 0.f, 0.f, 0.f};
  bf16x8 a1[4];
#pragma unroll
  for (int s = 0; s < 4; s++)
    a1[s] = *(const bf16x8*)(xb + (size_t)(n0 + lr) * 128 + s * 32 + g * 8);
#pragma unroll
  for (int s = 0; s < 4; s++) {
    bf16x8 w[10];
#pragma unroll
    for (int j = 0; j < 10; j++) w[j] = *(const bf16x8*)&W1f[(s * 20 + j) * 64 + lane];
#pragma unroll
    for (int j = 0; j < 10; j++)
      acc1[j] = __builtin_amdgcn_mfma_f32_16x16x32_bf16(w[j], a1[s], acc1[j], 0, 0, 0);
#pragma unroll
    for (int j = 0; j < 10; j++) w[j] = *(const bf16x8*)&W1f[(s * 20 + 10 + j) * 64 + lane];
#pragma unroll
    for (int j = 0; j < 10; j++)
      acc1[10 + j] = __builtin_amdgcn_mfma_f32_16x16x32_bf16(w[j], a1[s], acc1[10 + j], 0, 0, 0);
  }
  // h1 -> wave-private stage (bf16); cols 300..319 = 0 (zero W pad + bias)
#pragma unroll
  for (int j = 0; j < 20; j++) {
    float4 bv = *(const float4*)(b1pad + j * 16 + g * 4);
    unsigned lo = f2bf(fmaxf(acc1[j][0] + bv.x, 0.f)) |
                  (f2bf(fmaxf(acc1[j][1] + bv.y, 0.f)) << 16);
    unsigned hi = f2bf(fmaxf(acc1[j][2] + bv.z, 0.f)) |
                  (f2bf(fmaxf(acc1[j][3] + bv.w, 0.f)) << 16);
    uint2 pk; pk.x = lo; pk.y = hi;
    *(uint2*)(ost + lr * STG + j * 16 + g * 4) = pk;
  }

  // ---- mm2 ----
  f32x4 acc2[13];
#pragma unroll
  for (int j = 0; j < 13; j++) acc2[j] = (f32x4){0.f, 0.f, 0.f, 0.f};
#pragma unroll
  for (int s = 0; s < 10; s++) {
    bf16x8 a = *(const bf16x8*)(ost + lr * STG + s * 32 + g * 8);
    bf16x8 w[13];
#pragma unroll
    for (int j = 0; j < 13; j++) w[j] = *(const bf16x8*)&W2f[(s * 13 + j) * 64 + lane];
#pragma unroll
    for (int j = 0; j < 13; j++)
      acc2[j] = __builtin_amdgcn_mfma_f32_16x16x32_bf16(w[j], a, acc2[j], 0, 0, 0);
  }
  // out epilogue: reuse wave-private stage as [16][216] (same-wave LDS order)
#pragma unroll
  for (int j = 0; j < 13; j++) {
    unsigned lo = f2bf(acc2[j][0]) | (f2bf(acc2[j][1]) << 16);
    unsigned hi = f2bf(acc2[j][2]) | (f2bf(acc2[j][3]) << 16);
    uint2 pk; pk.x = lo; pk.y = hi;
    *(uint2*)(ost + lr * 216 + j * 16 + g * 4) = pk;
  }
  // wave tile rows n0..n0+15 x 208 cols = 6656 contiguous bytes (64B-aligned)
  uint4* gdst = (uint4*)(ga2b + (size_t)n0 * 208);
  for (int idx = lane; idx < 416; idx += 64) {
    int row = idx / 26, q = idx - row * 26;
    gdst[idx] = *(const uint4*)(ost + row * 216 + q * 8);
  }
}

// ---------------- launch ----------------
extern "C" void kernel_launch(void* const* d_in, const int* in_sizes, int n_in,
                              void* d_out, int out_size, void* d_ws, size_t ws_size,
                              hipStream_t stream) {
  const float* x  = (const float*)d_in[0];
  const int*   ei = (const int*)d_in[1];
  const float* W1 = (const float*)d_in[2];  // [2][58][300]
  const float* b1 = (const float*)d_in[3];
  const float* W2 = (const float*)d_in[4];  // [2][300][100]
  const float* b2 = (const float*)d_in[5];
  const float* W3 = (const float*)d_in[6];  // [2][100][1]
  const float* b3 = (const float*)d_in[7];
  float* out = (float*)d_out;

  const int N = in_sizes[0] / 58;            // 100000
  const int E = in_sizes[1] / 2;             // 800000
  const int NR = (N + 127) & ~127;           // 100096 (multiple of 64)
  const int NB = (N + 1023) / 1024;
  const int* src = ei;
  const int* dst = ei + E;

  char* ws = (char*)d_ws;
  size_t off = 0;
  auto alloc = [&](size_t bytes) -> void* {
    void* p = ws + off;
    off += (bytes + 255) & ~(size_t)255;
    return p;
  };
  unsigned* deg      = (unsigned*)alloc((size_t)2 * N * 4);
  unsigned* cnt      = deg + N;
  float*    dinv     = (float*)alloc((size_t)N * 4);
  unsigned* rowstart = (unsigned*)alloc((size_t)(N + 1) * 4);
  unsigned* rank     = (unsigned*)alloc((size_t)E * 4);
  unsigned* btot     = (unsigned*)alloc((size_t)256 * 4);
  int2*     er       = (int2*)alloc((size_t)E * 8);
  unsigned short* xb   = (unsigned short*)alloc((size_t)NR * 128 * 2);
  uint4*    W1f      = (uint4*)alloc((size_t)4 * 20 * 64 * 16);   // 80 KB
  uint4*    W2f      = (uint4*)alloc((size_t)10 * 13 * 64 * 16);  // 133 KB
  float*    b1pad    = (float*)alloc((size_t)320 * 4);
  unsigned short* ga2b = (unsigned short*)alloc((size_t)NR * 208 * 2);
  float* a3 = (float*)alloc((size_t)N * 4);
  float* g3 = (float*)alloc((size_t)N * 4);

  // --- CSR + dinv ---
  hipMemsetAsync(deg, 0, (size_t)2 * N * 4, stream);
  k_count<<<(E + 255) / 256, 256, 0, stream>>>(src, dst, deg, cnt, rank, E);
  k_dinv<<<(N + 255) / 256, 256, 0, stream>>>(deg, dinv, N);
  k_scan1<<<NB, 256, 0, stream>>>(cnt, btot, N);
  k_scan2<<<1, 256, 0, stream>>>(btot, rowstart, NB, N, E);
  k_scan3<<<NB, 256, 0, stream>>>(cnt, btot, rowstart, N);
  k_fill<<<(E + 255) / 256, 256, 0, stream>>>(src, dst, dinv, rowstart, rank, er, E);

  // --- preps ---
  k_prep_w1f<<<(4 * 20 * 64 + 255) / 256, 256, 0, stream>>>(W1, W1f);
  k_prep_w2f<<<(10 * 13 * 64 + 255) / 256, 256, 0, stream>>>(W2, W2f);
  k_prep_b1pad<<<2, 256, 0, stream>>>(b1, b1pad);
  k_prep_xb<<<((size_t)N * 64 + 255) / 256, 256, 0, stream>>>(x, xb, N);

  // --- layer 1+2 fused ---
  k_gather58<<<(N + 3) / 4, 256, 0, stream>>>(rowstart, er, dinv, xb, N);
  k_mm12_mfma<<<NR / 64, 256, 0, stream>>>(xb, W1f, W2f, b1pad, ga2b);
  k_gather_l2<<<(N + 3) / 4, 256, 0, stream>>>(rowstart, er, dinv, ga2b,
                                               b2, W3, W3 + 100, b3, a3, g3, N);

  // --- layer 3 ---
  k_gather1<<<(N + 255) / 256, 256, 0, stream>>>(rowstart, er, dinv, g3, a3, out, N);
}

// Round 13
// 339.483 us; speedup vs baseline: 1.1950x; 1.0248x over previous
//
#include <hip/hip_runtime.h>

// ---------------------------------------------------------------------------
// EMOGI ChebConv-K2 x3 : N=100000 nodes, E=800000 edges, dims 58->300->100->1
//   CSR by dst (count+rank / scan / fill-no-atomic) -> gathers.
//   xb  [NR][128] bf16 = [x | p1 | 0]       (p1 filled by gather58)
//   k_mm12: FUSED  h1 = relu([x|p1]@W1+b1) (wave-private LDS stage) ;
//           ga2b[NR][208] = h1 @ [W21|pad|W20|pad]
//   gather_l2: p2 = prop(g2); h2 = relu(a2+p2+b2) in-reg; a3,g3 = h2@W3 dots
//   gather1: out = a3 + prop(g3)
//
// R12 lesson: explicit w[13] arrays did NOT group the loads -- after unroll
// +SSA renaming the machine scheduler re-interleaves load->mfma pairwise to
// minimize live ranges (VGPR stayed 84; ~220 serial 300cyc L2 trips / 3
// waves/SIMD = the measured 111us). Dataflow can't force grouping;
// a SCHEDULER FENCE can: __builtin_amdgcn_sched_barrier(0) after each load
// loop pins "all group loads issued before any group mfma"; absence of a
// fence between mfma(s) and loads(s+1) lets them interleave = free SW pipe.
// ---------------------------------------------------------------------------

typedef short bf16x8 __attribute__((ext_vector_type(8)));
typedef float f32x4 __attribute__((ext_vector_type(4)));

__device__ __forceinline__ unsigned f2bf(float f) {  // RNE fp32->bf16 bits
  unsigned u = __float_as_uint(f);
  u += 0x7fff + ((u >> 16) & 1);
  return u >> 16;
}
__device__ __forceinline__ float bf2f(unsigned s) {
  return __uint_as_float(s << 16);
}

// ---------------- CSR build ----------------
__global__ void k_count(const int* __restrict__ src, const int* __restrict__ dst,
                        unsigned* __restrict__ deg, unsigned* __restrict__ cnt,
                        unsigned* __restrict__ rank, int E) {
  int i = blockIdx.x * blockDim.x + threadIdx.x;
  if (i < E) {
    atomicAdd(&deg[src[i]], 1u);
    rank[i] = atomicAdd(&cnt[dst[i]], 1u);
  }
}

__global__ void k_dinv(const unsigned* __restrict__ deg, float* __restrict__ dinv, int N) {
  int i = blockIdx.x * blockDim.x + threadIdx.x;
  if (i < N) {
    unsigned d = deg[i];
    dinv[i] = d ? rsqrtf((float)d) : 0.0f;
  }
}

__global__ __launch_bounds__(256) void k_scan1(const unsigned* __restrict__ cnt,
                                               unsigned* __restrict__ btot, int N) {
  __shared__ unsigned s[256];
  int b = blockIdx.x, t = threadIdx.x;
  int base = b * 1024;
  unsigned sum = 0;
  for (int i = t; i < 1024; i += 256) {
    int idx = base + i;
    sum += (idx < N) ? cnt[idx] : 0u;
  }
  s[t] = sum;
  __syncthreads();
  for (int off = 128; off > 0; off >>= 1) {
    if (t < off) s[t] += s[t + off];
    __syncthreads();
  }
  if (t == 0) btot[b] = s[0];
}

__global__ __launch_bounds__(256) void k_scan2(unsigned* __restrict__ btot,
                                               unsigned* __restrict__ rowstart,
                                               int NB, int N, int E) {
  __shared__ unsigned s[256];
  int t = threadIdx.x;
  s[t] = (t < NB) ? btot[t] : 0u;
  __syncthreads();
  if (t == 0) {
    unsigned acc = 0;
    for (int i = 0; i < NB; i++) { unsigned v = s[i]; s[i] = acc; acc += v; }
  }
  __syncthreads();
  if (t < NB) btot[t] = s[t];
  if (t == 0) rowstart[N] = (unsigned)E;
}

__global__ __launch_bounds__(256) void k_scan3(const unsigned* __restrict__ cnt,
                                               const unsigned* __restrict__ btot,
                                               unsigned* __restrict__ rowstart, int N) {
  __shared__ unsigned ssum[256];
  int b = blockIdx.x, t = threadIdx.x;
  int base = b * 1024 + t * 4;
  unsigned v0 = 0, v1 = 0, v2 = 0, v3 = 0;
  if (base + 0 < N) v0 = cnt[base + 0];
  if (base + 1 < N) v1 = cnt[base + 1];
  if (base + 2 < N) v2 = cnt[base + 2];
  if (base + 3 < N) v3 = cnt[base + 3];
  ssum[t] = v0 + v1 + v2 + v3;
  __syncthreads();
  for (int off = 1; off < 256; off <<= 1) {
    unsigned add = (t >= off) ? ssum[t - off] : 0u;
    __syncthreads();
    ssum[t] += add;
    __syncthreads();
  }
  unsigned texcl = ((t == 0) ? 0u : ssum[t - 1]) + btot[b];
  unsigned r0 = texcl, r1 = r0 + v0, r2 = r1 + v1, r3 = r2 + v2;
  if (base + 0 < N) rowstart[base + 0] = r0;
  if (base + 1 < N) rowstart[base + 1] = r1;
  if (base + 2 < N) rowstart[base + 2] = r2;
  if (base + 3 < N) rowstart[base + 3] = r3;
}

// fill without atomics: position = rowstart[dst] + rank (from k_count)
__global__ void k_fill(const int* __restrict__ src, const int* __restrict__ dst,
                       const float* __restrict__ dinv, const unsigned* __restrict__ rowstart,
                       const unsigned* __restrict__ rank, int2* __restrict__ er, int E) {
  int e = blockIdx.x * blockDim.x + threadIdx.x;
  if (e >= E) return;
  int s = src[e], d = dst[e];
  er[rowstart[d] + rank[e]] = make_int2(s, __float_as_int(dinv[s]));
}

// ---------------- prep kernels ----------------
__global__ void k_prep_xb(const float* __restrict__ x, unsigned short* __restrict__ xb, int N) {
  int idx = blockIdx.x * blockDim.x + threadIdx.x;
  int n = idx >> 6, p = idx & 63;
  if (n >= N) return;
  int c = p * 2;
  if (c < 58) {
    unsigned lo = f2bf(x[(size_t)n * 58 + c]);
    unsigned hi = f2bf(x[(size_t)n * 58 + c + 1]);
    *(unsigned*)(xb + (size_t)n * 128 + c) = lo | (hi << 16);
  } else if (c >= 116) {
    *(unsigned*)(xb + (size_t)n * 128 + c) = 0;
  }
}

// W1f fragment-packed [s<4][j<20][lane<64][8 bf16]
__global__ void k_prep_w1f(const float* __restrict__ W1, uint4* __restrict__ W1f) {
  int idx = blockIdx.x * blockDim.x + threadIdx.x;
  if (idx >= 4 * 20 * 64) return;
  int lane = idx & 63, j = (idx >> 6) % 20, s = (idx >> 6) / 20;
  int lr = lane & 15, g = lane >> 4;
  int c = j * 16 + lr;
  unsigned short v[8];
#pragma unroll
  for (int i = 0; i < 8; i++) {
    int k = s * 32 + g * 8 + i;
    float f = 0.0f;
    if (c < 300 && k < 116)
      f = (k < 58) ? W1[k * 300 + c] : W1[17400 + (k - 58) * 300 + c];
    v[i] = (unsigned short)f2bf(f);
  }
  W1f[idx] = *(const uint4*)v;
}

// W2f fragment-packed [s<10][j<13][lane<64][8 bf16]
__global__ void k_prep_w2f(const float* __restrict__ W2, uint4* __restrict__ W2f) {
  int idx = blockIdx.x * blockDim.x + threadIdx.x;
  if (idx >= 10 * 13 * 64) return;
  int lane = idx & 63, j = (idx >> 6) % 13, s = (idx >> 6) / 13;
  int lr = lane & 15, g = lane >> 4;
  int r = j * 16 + lr;
  unsigned short v[8];
#pragma unroll
  for (int i = 0; i < 8; i++) {
    int k = s * 32 + g * 8 + i;
    float f = 0.0f;
    if (k < 300) {
      if (r < 100) f = W2[30000 + k * 100 + r];
      else if (r >= 104 && r < 204) f = W2[k * 100 + (r - 104)];
    }
    v[i] = (unsigned short)f2bf(f);
  }
  W2f[idx] = *(const uint4*)v;
}

__global__ void k_prep_b1pad(const float* __restrict__ b1, float* __restrict__ b1pad) {
  int t = blockIdx.x * blockDim.x + threadIdx.x;
  if (t < 320) b1pad[t] = (t < 300) ? b1[t] : 0.0f;
}

// ---------------- gathers (x4 MLP-unrolled) ----------------
__global__ __launch_bounds__(256) void k_gather58(
    const unsigned* __restrict__ rowstart, const int2* __restrict__ er,
    const float* __restrict__ dinv, unsigned short* __restrict__ xb, int N) {
  int wid = (blockIdx.x * blockDim.x + threadIdx.x) >> 6;
  if (wid >= N) return;
  int lane = threadIdx.x & 63;
  int c0 = lane * 2;
  if (c0 >= 58) return;
  unsigned s0 = rowstart[wid], s1 = rowstart[wid + 1];
  float a0 = 0.f, a1 = 0.f, b0 = 0.f, b1 = 0.f;
  float c0a = 0.f, c1a = 0.f, d0 = 0.f, d1 = 0.f;
  unsigned e = s0;
  for (; e + 4 <= s1; e += 4) {
    int2 r0 = er[e], r1 = er[e + 1], r2 = er[e + 2], r3 = er[e + 3];
    unsigned v0 = *(const unsigned*)(xb + (size_t)r0.x * 128 + c0);
    unsigned v1 = *(const unsigned*)(xb + (size_t)r1.x * 128 + c0);
    unsigned v2 = *(const unsigned*)(xb + (size_t)r2.x * 128 + c0);
    unsigned v3 = *(const unsigned*)(xb + (size_t)r3.x * 128 + c0);
    float w0 = __int_as_float(r0.y), w1 = __int_as_float(r1.y);
    float w2 = __int_as_float(r2.y), w3 = __int_as_float(r3.y);
    a0 += w0 * bf2f(v0 & 0xffffu); a1 += w0 * bf2f(v0 >> 16);
    b0 += w1 * bf2f(v1 & 0xffffu); b1 += w1 * bf2f(v1 >> 16);
    c0a += w2 * bf2f(v2 & 0xffffu); c1a += w2 * bf2f(v2 >> 16);
    d0 += w3 * bf2f(v3 & 0xffffu); d1 += w3 * bf2f(v3 >> 16);
  }
  for (; e < s1; ++e) {
    int2 r = er[e];
    float w = __int_as_float(r.y);
    unsigned v = *(const unsigned*)(xb + (size_t)r.x * 128 + c0);
    a0 += w * bf2f(v & 0xffffu); a1 += w * bf2f(v >> 16);
  }
  float dd = -dinv[wid];
  float p0 = dd * ((a0 + b0) + (c0a + d0));
  float p1 = dd * ((a1 + b1) + (c1a + d1));
  *(unsigned*)(xb + (size_t)wid * 128 + 58 + c0) = f2bf(p0) | (f2bf(p1) << 16);
}

// layer2 tail fused: p2 = prop(g2); h2 = relu(a2+p2+b2); a3,g3 = h2@W30/W31
__global__ __launch_bounds__(256) void k_gather_l2(
    const unsigned* __restrict__ rowstart, const int2* __restrict__ er,
    const float* __restrict__ dinv, const unsigned short* __restrict__ ga2b,
    const float* __restrict__ b2, const float* __restrict__ W30,
    const float* __restrict__ W31, const float* __restrict__ b3,
    float* __restrict__ a3, float* __restrict__ g3, int N) {
  int wid = (blockIdx.x * blockDim.x + threadIdx.x) >> 6;
  if (wid >= N) return;
  int lane = threadIdx.x & 63;
  int c0 = lane * 2;
  bool act = c0 < 100;
  unsigned s0 = rowstart[wid], s1 = rowstart[wid + 1];
  float aa = 0.f, gg = 0.f;
  if (act) {
    float a0 = 0.f, a1 = 0.f, b0 = 0.f, b1 = 0.f;
    float c0a = 0.f, c1a = 0.f, d0 = 0.f, d1 = 0.f;
    unsigned e = s0;
    for (; e + 4 <= s1; e += 4) {
      int2 r0 = er[e], r1 = er[e + 1], r2 = er[e + 2], r3 = er[e + 3];
      unsigned v0 = *(const unsigned*)(ga2b + (size_t)r0.x * 208 + c0);
      unsigned v1 = *(const unsigned*)(ga2b + (size_t)r1.x * 208 + c0);
      unsigned v2 = *(const unsigned*)(ga2b + (size_t)r2.x * 208 + c0);
      unsigned v3 = *(const unsigned*)(ga2b + (size_t)r3.x * 208 + c0);
      float w0 = __int_as_float(r0.y), w1 = __int_as_float(r1.y);
      float w2 = __int_as_float(r2.y), w3 = __int_as_float(r3.y);
      a0 += w0 * bf2f(v0 & 0xffffu); a1 += w0 * bf2f(v0 >> 16);
      b0 += w1 * bf2f(v1 & 0xffffu); b1 += w1 * bf2f(v1 >> 16);
      c0a += w2 * bf2f(v2 & 0xffffu); c1a += w2 * bf2f(v2 >> 16);
      d0 += w3 * bf2f(v3 & 0xffffu); d1 += w3 * bf2f(v3 >> 16);
    }
    for (; e < s1; ++e) {
      int2 r = er[e];
      float w = __int_as_float(r.y);
      unsigned v = *(const unsigned*)(ga2b + (size_t)r.x * 208 + c0);
      a0 += w * bf2f(v & 0xffffu); a1 += w * bf2f(v >> 16);
    }
    float dd = -dinv[wid];
    float p0 = dd * ((a0 + b0) + (c0a + d0));
    float p1 = dd * ((a1 + b1) + (c1a + d1));
    unsigned av = *(const unsigned*)(ga2b + (size_t)wid * 208 + 104 + c0);
    float h0 = fmaxf(bf2f(av & 0xffffu) + p0 + b2[c0], 0.f);
    float h1 = fmaxf(bf2f(av >> 16) + p1 + b2[c0 + 1], 0.f);
    aa = h0 * W30[c0] + h1 * W30[c0 + 1];
    gg = h0 * W31[c0] + h1 * W31[c0 + 1];
  }
#pragma unroll
  for (int off = 32; off > 0; off >>= 1) {
    aa += __shfl_xor(aa, off);
    gg += __shfl_xor(gg, off);
  }
  if (lane == 0) {
    a3[wid] = aa + b3[0];
    g3[wid] = gg;
  }
}

__global__ void k_gather1(const unsigned* __restrict__ rowstart, const int2* __restrict__ er,
                          const float* __restrict__ dinv, const float* __restrict__ g3,
                          const float* __restrict__ a3, float* __restrict__ out, int N) {
  int n = blockIdx.x * blockDim.x + threadIdx.x;
  if (n >= N) return;
  unsigned s0 = rowstart[n], s1 = rowstart[n + 1];
  float a = 0.f, b = 0.f, c = 0.f, d = 0.f;
  unsigned e = s0;
  for (; e + 4 <= s1; e += 4) {
    int2 r0 = er[e], r1 = er[e + 1], r2 = er[e + 2], r3 = er[e + 3];
    float g0 = g3[r0.x], g1 = g3[r1.x], g2v = g3[r2.x], g3v = g3[r3.x];
    a += __int_as_float(r0.y) * g0;
    b += __int_as_float(r1.y) * g1;
    c += __int_as_float(r2.y) * g2v;
    d += __int_as_float(r3.y) * g3v;
  }
  for (; e < s1; ++e) {
    int2 r = er[e];
    a += __int_as_float(r.y) * g3[r.x];
  }
  out[n] = a3[n] - dinv[n] * ((a + b) + (c + d));
}

// ---------------- FUSED MFMA layer1+layer2 (sched_barrier-pinned groups) ----
// Per wave (16 nodes), independent, no __syncthreads. Load groups are pinned
// with sched_barrier(0) AFTER each load loop: all 10-13 loads issue before
// any consuming mfma (one L2 latency per group, not per mfma). No fence
// between mfma(s) and loads(s+1) -> they interleave = software pipeline.
#define STG 324  // 648B row stride
__global__ __launch_bounds__(256, 3) void k_mm12_mfma(
    const unsigned short* __restrict__ xb, const uint4* __restrict__ W1f,
    const uint4* __restrict__ W2f, const float* __restrict__ b1pad,
    unsigned short* __restrict__ ga2b) {
  __shared__ unsigned short stage[4 * 16 * STG];  // 41.5 KB -> 3 blk/CU
  int tid = threadIdx.x;
  int lane = tid & 63, wv = tid >> 6, lr = lane & 15, g = lane >> 4;
  int n0 = blockIdx.x * 64 + wv * 16;
  unsigned short* ost = stage + wv * 16 * STG;

  // ---- mm1 ----
  f32x4 acc1[20];
#pragma unroll
  for (int j = 0; j < 20; j++) acc1[j] = (f32x4){0.f, 0.f, 0.f, 0.f};
  bf16x8 a1[4];
#pragma unroll
  for (int s = 0; s < 4; s++)
    a1[s] = *(const bf16x8*)(xb + (size_t)(n0 + lr) * 128 + s * 32 + g * 8);
#pragma unroll
  for (int s = 0; s < 4; s++) {
    bf16x8 w[10];
#pragma unroll
    for (int j = 0; j < 10; j++) w[j] = *(const bf16x8*)&W1f[(s * 20 + j) * 64 + lane];
    __builtin_amdgcn_sched_barrier(0);  // pin: all 10 loads before any mfma
#pragma unroll
    for (int j = 0; j < 10; j++)
      acc1[j] = __builtin_amdgcn_mfma_f32_16x16x32_bf16(w[j], a1[s], acc1[j], 0, 0, 0);
    bf16x8 w2[10];
#pragma unroll
    for (int j = 0; j < 10; j++) w2[j] = *(const bf16x8*)&W1f[(s * 20 + 10 + j) * 64 + lane];
    __builtin_amdgcn_sched_barrier(0);
#pragma unroll
    for (int j = 0; j < 10; j++)
      acc1[10 + j] = __builtin_amdgcn_mfma_f32_16x16x32_bf16(w2[j], a1[s], acc1[10 + j], 0, 0, 0);
  }
  // h1 -> wave-private stage (bf16); cols 300..319 = 0 (zero W pad + bias)
#pragma unroll
  for (int j = 0; j < 20; j++) {
    float4 bv = *(const float4*)(b1pad + j * 16 + g * 4);
    unsigned lo = f2bf(fmaxf(acc1[j][0] + bv.x, 0.f)) |
                  (f2bf(fmaxf(acc1[j][1] + bv.y, 0.f)) << 16);
    unsigned hi = f2bf(fmaxf(acc1[j][2] + bv.z, 0.f)) |
                  (f2bf(fmaxf(acc1[j][3] + bv.w, 0.f)) << 16);
    uint2 pk; pk.x = lo; pk.y = hi;
    *(uint2*)(ost + lr * STG + j * 16 + g * 4) = pk;
  }

  // ---- mm2 ----
  f32x4 acc2[13];
#pragma unroll
  for (int j = 0; j < 13; j++) acc2[j] = (f32x4){0.f, 0.f, 0.f, 0.f};
#pragma unroll
  for (int s = 0; s < 10; s++) {
    bf16x8 a = *(const bf16x8*)(ost + lr * STG + s * 32 + g * 8);
    bf16x8 w[13];
#pragma unroll
    for (int j = 0; j < 13; j++) w[j] = *(const bf16x8*)&W2f[(s * 13 + j) * 64 + lane];
    __builtin_amdgcn_sched_barrier(0);  // pin: all 13 loads before any mfma
#pragma unroll
    for (int j = 0; j < 13; j++)
      acc2[j] = __builtin_amdgcn_mfma_f32_16x16x32_bf16(w[j], a, acc2[j], 0, 0, 0);
  }
  // out epilogue: reuse wave-private stage as [16][216] (same-wave LDS order)
#pragma unroll
  for (int j = 0; j < 13; j++) {
    unsigned lo = f2bf(acc2[j][0]) | (f2bf(acc2[j][1]) << 16);
    unsigned hi = f2bf(acc2[j][2]) | (f2bf(acc2[j][3]) << 16);
    uint2 pk; pk.x = lo; pk.y = hi;
    *(uint2*)(ost + lr * 216 + j * 16 + g * 4) = pk;
  }
  // wave tile rows n0..n0+15 x 208 cols = 6656 contiguous bytes (64B-aligned)
  uint4* gdst = (uint4*)(ga2b + (size_t)n0 * 208);
  for (int idx = lane; idx < 416; idx += 64) {
    int row = idx / 26, q = idx - row * 26;
    gdst[idx] = *(const uint4*)(ost + row * 216 + q * 8);
  }
}

// ---------------- launch ----------------
extern "C" void kernel_launch(void* const* d_in, const int* in_sizes, int n_in,
                              void* d_out, int out_size, void* d_ws, size_t ws_size,
                              hipStream_t stream) {
  const float* x  = (const float*)d_in[0];
  const int*   ei = (const int*)d_in[1];
  const float* W1 = (const float*)d_in[2];  // [2][58][300]
  const float* b1 = (const float*)d_in[3];
  const float* W2 = (const float*)d_in[4];  // [2][300][100]
  const float* b2 = (const float*)d_in[5];
  const float* W3 = (const float*)d_in[6];  // [2][100][1]
  const float* b3 = (const float*)d_in[7];
  float* out = (float*)d_out;

  const int N = in_sizes[0] / 58;            // 100000
  const int E = in_sizes[1] / 2;             // 800000
  const int NR = (N + 127) & ~127;           // 100096 (multiple of 64)
  const int NB = (N + 1023) / 1024;
  const int* src = ei;
  const int* dst = ei + E;

  char* ws = (char*)d_ws;
  size_t off = 0;
  auto alloc = [&](size_t bytes) -> void* {
    void* p = ws + off;
    off += (bytes + 255) & ~(size_t)255;
    return p;
  };
  unsigned* deg      = (unsigned*)alloc((size_t)2 * N * 4);
  unsigned* cnt      = deg + N;
  float*    dinv     = (float*)alloc((size_t)N * 4);
  unsigned* rowstart = (unsigned*)alloc((size_t)(N + 1) * 4);
  unsigned* rank     = (unsigned*)alloc((size_t)E * 4);
  unsigned* btot     = (unsigned*)alloc((size_t)256 * 4);
  int2*     er       = (int2*)alloc((size_t)E * 8);
  unsigned short* xb   = (unsigned short*)alloc((size_t)NR * 128 * 2);
  uint4*    W1f      = (uint4*)alloc((size_t)4 * 20 * 64 * 16);   // 80 KB
  uint4*    W2f      = (uint4*)alloc((size_t)10 * 13 * 64 * 16);  // 133 KB
  float*    b1pad    = (float*)alloc((size_t)320 * 4);
  unsigned short* ga2b = (unsigned short*)alloc((size_t)NR * 208 * 2);
  float* a3 = (float*)alloc((size_t)N * 4);
  float* g3 = (float*)alloc((size_t)N * 4);

  // --- CSR + dinv ---
  hipMemsetAsync(deg, 0, (size_t)2 * N * 4, stream);
  k_count<<<(E + 255) / 256, 256, 0, stream>>>(src, dst, deg, cnt, rank, E);
  k_dinv<<<(N + 255) / 256, 256, 0, stream>>>(deg, dinv, N);
  k_scan1<<<NB, 256, 0, stream>>>(cnt, btot, N);
  k_scan2<<<1, 256, 0, stream>>>(btot, rowstart, NB, N, E);
  k_scan3<<<NB, 256, 0, stream>>>(cnt, btot, rowstart, N);
  k_fill<<<(E + 255) / 256, 256, 0, stream>>>(src, dst, dinv, rowstart, rank, er, E);

  // --- preps ---
  k_prep_w1f<<<(4 * 20 * 64 + 255) / 256, 256, 0, stream>>>(W1, W1f);
  k_prep_w2f<<<(10 * 13 * 64 + 255) / 256, 256, 0, stream>>>(W2, W2f);
  k_prep_b1pad<<<2, 256, 0, stream>>>(b1, b1pad);
  k_prep_xb<<<((size_t)N * 64 + 255) / 256, 256, 0, stream>>>(x, xb, N);

  // --- layer 1+2 fused ---
  k_gather58<<<(N + 3) / 4, 256, 0, stream>>>(rowstart, er, dinv, xb, N);
  k_mm12_mfma<<<NR / 64, 256, 0, stream>>>(xb, W1f, W2f, b1pad, ga2b);
  k_gather_l2<<<(N + 3) / 4, 256, 0, stream>>>(rowstart, er, dinv, ga2b,
                                               b2, W3, W3 + 100, b3, a3, g3, N);

  // --- layer 3 ---
  k_gather1<<<(N + 255) / 256, 256, 0, stream>>>(rowstart, er, dinv, g3, a3, out, N);
}

// Round 14
// 304.950 us; speedup vs baseline: 1.3303x; 1.1132x over previous
//
#include <hip/hip_runtime.h>

// ---------------------------------------------------------------------------
// EMOGI ChebConv-K2 x3 : N=100000 nodes, E=800000 edges, dims 58->300->100->1
//   CSR by dst (count+rank / scan / fill-no-atomic) -> gathers.
//   xb  [NR][128] bf16 = [x | p1 | 0]       (p1 filled by gather58)
//   k_mm12: FUSED  h1 = relu([x|p1]@W1+b1) (wave-private LDS stage) ;
//           ga2b[NR][208] = h1 @ [W21|pad|W20|pad]
//   gather_l2: p2 = prop(g2); h2 = relu(a2+p2+b2) in-reg; a3,g3 = h2@W3 dots
//   gather1: out = a3 + prop(g3)
//
// R13 lesson: the fused wave was register-OVERSUBSCRIBED by design --
// acc1[20]+acc2[13] = 132 regs of accumulator + 40-52-reg load group vs the
// ~168 cap at 3 waves/SIMD. Compiler couldn't group loads (VGPR pinned 84);
// when sched_barrier forced it, it SPILLED (WRITE_SIZE 68->111MB = scratch).
// Fix: PHASE the accumulators -- mm1 in two 10-j halves, mm2 in 7-j + 6-j
// chunks over full K (acc dies between chunks; W loaded once total; stage
// re-read is cheap LDS). Chunk-1 output packed to registers so the
// out-stage write happens after the last h1 stage read. Peak live ~120 regs
// -> pinned load groups fit without spilling.
// ---------------------------------------------------------------------------

typedef short bf16x8 __attribute__((ext_vector_type(8)));
typedef float f32x4 __attribute__((ext_vector_type(4)));

__device__ __forceinline__ unsigned f2bf(float f) {  // RNE fp32->bf16 bits
  unsigned u = __float_as_uint(f);
  u += 0x7fff + ((u >> 16) & 1);
  return u >> 16;
}
__device__ __forceinline__ float bf2f(unsigned s) {
  return __uint_as_float(s << 16);
}

// ---------------- CSR build ----------------
__global__ void k_count(const int* __restrict__ src, const int* __restrict__ dst,
                        unsigned* __restrict__ deg, unsigned* __restrict__ cnt,
                        unsigned* __restrict__ rank, int E) {
  int i = blockIdx.x * blockDim.x + threadIdx.x;
  if (i < E) {
    atomicAdd(&deg[src[i]], 1u);
    rank[i] = atomicAdd(&cnt[dst[i]], 1u);
  }
}

__global__ void k_dinv(const unsigned* __restrict__ deg, float* __restrict__ dinv, int N) {
  int i = blockIdx.x * blockDim.x + threadIdx.x;
  if (i < N) {
    unsigned d = deg[i];
    dinv[i] = d ? rsqrtf((float)d) : 0.0f;
  }
}

__global__ __launch_bounds__(256) void k_scan1(const unsigned* __restrict__ cnt,
                                               unsigned* __restrict__ btot, int N) {
  __shared__ unsigned s[256];
  int b = blockIdx.x, t = threadIdx.x;
  int base = b * 1024;
  unsigned sum = 0;
  for (int i = t; i < 1024; i += 256) {
    int idx = base + i;
    sum += (idx < N) ? cnt[idx] : 0u;
  }
  s[t] = sum;
  __syncthreads();
  for (int off = 128; off > 0; off >>= 1) {
    if (t < off) s[t] += s[t + off];
    __syncthreads();
  }
  if (t == 0) btot[b] = s[0];
}

__global__ __launch_bounds__(256) void k_scan2(unsigned* __restrict__ btot,
                                               unsigned* __restrict__ rowstart,
                                               int NB, int N, int E) {
  __shared__ unsigned s[256];
  int t = threadIdx.x;
  s[t] = (t < NB) ? btot[t] : 0u;
  __syncthreads();
  if (t == 0) {
    unsigned acc = 0;
    for (int i = 0; i < NB; i++) { unsigned v = s[i]; s[i] = acc; acc += v; }
  }
  __syncthreads();
  if (t < NB) btot[t] = s[t];
  if (t == 0) rowstart[N] = (unsigned)E;
}

__global__ __launch_bounds__(256) void k_scan3(const unsigned* __restrict__ cnt,
                                               const unsigned* __restrict__ btot,
                                               unsigned* __restrict__ rowstart, int N) {
  __shared__ unsigned ssum[256];
  int b = blockIdx.x, t = threadIdx.x;
  int base = b * 1024 + t * 4;
  unsigned v0 = 0, v1 = 0, v2 = 0, v3 = 0;
  if (base + 0 < N) v0 = cnt[base + 0];
  if (base + 1 < N) v1 = cnt[base + 1];
  if (base + 2 < N) v2 = cnt[base + 2];
  if (base + 3 < N) v3 = cnt[base + 3];
  ssum[t] = v0 + v1 + v2 + v3;
  __syncthreads();
  for (int off = 1; off < 256; off <<= 1) {
    unsigned add = (t >= off) ? ssum[t - off] : 0u;
    __syncthreads();
    ssum[t] += add;
    __syncthreads();
  }
  unsigned texcl = ((t == 0) ? 0u : ssum[t - 1]) + btot[b];
  unsigned r0 = texcl, r1 = r0 + v0, r2 = r1 + v1, r3 = r2 + v2;
  if (base + 0 < N) rowstart[base + 0] = r0;
  if (base + 1 < N) rowstart[base + 1] = r1;
  if (base + 2 < N) rowstart[base + 2] = r2;
  if (base + 3 < N) rowstart[base + 3] = r3;
}

// fill without atomics: position = rowstart[dst] + rank (from k_count)
__global__ void k_fill(const int* __restrict__ src, const int* __restrict__ dst,
                       const float* __restrict__ dinv, const unsigned* __restrict__ rowstart,
                       const unsigned* __restrict__ rank, int2* __restrict__ er, int E) {
  int e = blockIdx.x * blockDim.x + threadIdx.x;
  if (e >= E) return;
  int s = src[e], d = dst[e];
  er[rowstart[d] + rank[e]] = make_int2(s, __float_as_int(dinv[s]));
}

// ---------------- prep kernels ----------------
__global__ void k_prep_xb(const float* __restrict__ x, unsigned short* __restrict__ xb, int N) {
  int idx = blockIdx.x * blockDim.x + threadIdx.x;
  int n = idx >> 6, p = idx & 63;
  if (n >= N) return;
  int c = p * 2;
  if (c < 58) {
    unsigned lo = f2bf(x[(size_t)n * 58 + c]);
    unsigned hi = f2bf(x[(size_t)n * 58 + c + 1]);
    *(unsigned*)(xb + (size_t)n * 128 + c) = lo | (hi << 16);
  } else if (c >= 116) {
    *(unsigned*)(xb + (size_t)n * 128 + c) = 0;
  }
}

// W1f fragment-packed [s<4][j<20][lane<64][8 bf16]
__global__ void k_prep_w1f(const float* __restrict__ W1, uint4* __restrict__ W1f) {
  int idx = blockIdx.x * blockDim.x + threadIdx.x;
  if (idx >= 4 * 20 * 64) return;
  int lane = idx & 63, j = (idx >> 6) % 20, s = (idx >> 6) / 20;
  int lr = lane & 15, g = lane >> 4;
  int c = j * 16 + lr;
  unsigned short v[8];
#pragma unroll
  for (int i = 0; i < 8; i++) {
    int k = s * 32 + g * 8 + i;
    float f = 0.0f;
    if (c < 300 && k < 116)
      f = (k < 58) ? W1[k * 300 + c] : W1[17400 + (k - 58) * 300 + c];
    v[i] = (unsigned short)f2bf(f);
  }
  W1f[idx] = *(const uint4*)v;
}

// W2f fragment-packed [s<10][j<13][lane<64][8 bf16]
__global__ void k_prep_w2f(const float* __restrict__ W2, uint4* __restrict__ W2f) {
  int idx = blockIdx.x * blockDim.x + threadIdx.x;
  if (idx >= 10 * 13 * 64) return;
  int lane = idx & 63, j = (idx >> 6) % 13, s = (idx >> 6) / 13;
  int lr = lane & 15, g = lane >> 4;
  int r = j * 16 + lr;
  unsigned short v[8];
#pragma unroll
  for (int i = 0; i < 8; i++) {
    int k = s * 32 + g * 8 + i;
    float f = 0.0f;
    if (k < 300) {
      if (r < 100) f = W2[30000 + k * 100 + r];
      else if (r >= 104 && r < 204) f = W2[k * 100 + (r - 104)];
    }
    v[i] = (unsigned short)f2bf(f);
  }
  W2f[idx] = *(const uint4*)v;
}

__global__ void k_prep_b1pad(const float* __restrict__ b1, float* __restrict__ b1pad) {
  int t = blockIdx.x * blockDim.x + threadIdx.x;
  if (t < 320) b1pad[t] = (t < 300) ? b1[t] : 0.0f;
}

// ---------------- gathers (x4 MLP-unrolled) ----------------
__global__ __launch_bounds__(256) void k_gather58(
    const unsigned* __restrict__ rowstart, const int2* __restrict__ er,
    const float* __restrict__ dinv, unsigned short* __restrict__ xb, int N) {
  int wid = (blockIdx.x * blockDim.x + threadIdx.x) >> 6;
  if (wid >= N) return;
  int lane = threadIdx.x & 63;
  int c0 = lane * 2;
  if (c0 >= 58) return;
  unsigned s0 = rowstart[wid], s1 = rowstart[wid + 1];
  float a0 = 0.f, a1 = 0.f, b0 = 0.f, b1 = 0.f;
  float c0a = 0.f, c1a = 0.f, d0 = 0.f, d1 = 0.f;
  unsigned e = s0;
  for (; e + 4 <= s1; e += 4) {
    int2 r0 = er[e], r1 = er[e + 1], r2 = er[e + 2], r3 = er[e + 3];
    unsigned v0 = *(const unsigned*)(xb + (size_t)r0.x * 128 + c0);
    unsigned v1 = *(const unsigned*)(xb + (size_t)r1.x * 128 + c0);
    unsigned v2 = *(const unsigned*)(xb + (size_t)r2.x * 128 + c0);
    unsigned v3 = *(const unsigned*)(xb + (size_t)r3.x * 128 + c0);
    float w0 = __int_as_float(r0.y), w1 = __int_as_float(r1.y);
    float w2 = __int_as_float(r2.y), w3 = __int_as_float(r3.y);
    a0 += w0 * bf2f(v0 & 0xffffu); a1 += w0 * bf2f(v0 >> 16);
    b0 += w1 * bf2f(v1 & 0xffffu); b1 += w1 * bf2f(v1 >> 16);
    c0a += w2 * bf2f(v2 & 0xffffu); c1a += w2 * bf2f(v2 >> 16);
    d0 += w3 * bf2f(v3 & 0xffffu); d1 += w3 * bf2f(v3 >> 16);
  }
  for (; e < s1; ++e) {
    int2 r = er[e];
    float w = __int_as_float(r.y);
    unsigned v = *(const unsigned*)(xb + (size_t)r.x * 128 + c0);
    a0 += w * bf2f(v & 0xffffu); a1 += w * bf2f(v >> 16);
  }
  float dd = -dinv[wid];
  float p0 = dd * ((a0 + b0) + (c0a + d0));
  float p1 = dd * ((a1 + b1) + (c1a + d1));
  *(unsigned*)(xb + (size_t)wid * 128 + 58 + c0) = f2bf(p0) | (f2bf(p1) << 16);
}

// layer2 tail fused: p2 = prop(g2); h2 = relu(a2+p2+b2); a3,g3 = h2@W30/W31
__global__ __launch_bounds__(256) void k_gather_l2(
    const unsigned* __restrict__ rowstart, const int2* __restrict__ er,
    const float* __restrict__ dinv, const unsigned short* __restrict__ ga2b,
    const float* __restrict__ b2, const float* __restrict__ W30,
    const float* __restrict__ W31, const float* __restrict__ b3,
    float* __restrict__ a3, float* __restrict__ g3, int N) {
  int wid = (blockIdx.x * blockDim.x + threadIdx.x) >> 6;
  if (wid >= N) return;
  int lane = threadIdx.x & 63;
  int c0 = lane * 2;
  bool act = c0 < 100;
  unsigned s0 = rowstart[wid], s1 = rowstart[wid + 1];
  float aa = 0.f, gg = 0.f;
  if (act) {
    float a0 = 0.f, a1 = 0.f, b0 = 0.f, b1 = 0.f;
    float c0a = 0.f, c1a = 0.f, d0 = 0.f, d1 = 0.f;
    unsigned e = s0;
    for (; e + 4 <= s1; e += 4) {
      int2 r0 = er[e], r1 = er[e + 1], r2 = er[e + 2], r3 = er[e + 3];
      unsigned v0 = *(const unsigned*)(ga2b + (size_t)r0.x * 208 + c0);
      unsigned v1 = *(const unsigned*)(ga2b + (size_t)r1.x * 208 + c0);
      unsigned v2 = *(const unsigned*)(ga2b + (size_t)r2.x * 208 + c0);
      unsigned v3 = *(const unsigned*)(ga2b + (size_t)r3.x * 208 + c0);
      float w0 = __int_as_float(r0.y), w1 = __int_as_float(r1.y);
      float w2 = __int_as_float(r2.y), w3 = __int_as_float(r3.y);
      a0 += w0 * bf2f(v0 & 0xffffu); a1 += w0 * bf2f(v0 >> 16);
      b0 += w1 * bf2f(v1 & 0xffffu); b1 += w1 * bf2f(v1 >> 16);
      c0a += w2 * bf2f(v2 & 0xffffu); c1a += w2 * bf2f(v2 >> 16);
      d0 += w3 * bf2f(v3 & 0xffffu); d1 += w3 * bf2f(v3 >> 16);
    }
    for (; e < s1; ++e) {
      int2 r = er[e];
      float w = __int_as_float(r.y);
      unsigned v = *(const unsigned*)(ga2b + (size_t)r.x * 208 + c0);
      a0 += w * bf2f(v & 0xffffu); a1 += w * bf2f(v >> 16);
    }
    float dd = -dinv[wid];
    float p0 = dd * ((a0 + b0) + (c0a + d0));
    float p1 = dd * ((a1 + b1) + (c1a + d1));
    unsigned av = *(const unsigned*)(ga2b + (size_t)wid * 208 + 104 + c0);
    float h0 = fmaxf(bf2f(av & 0xffffu) + p0 + b2[c0], 0.f);
    float h1 = fmaxf(bf2f(av >> 16) + p1 + b2[c0 + 1], 0.f);
    aa = h0 * W30[c0] + h1 * W30[c0 + 1];
    gg = h0 * W31[c0] + h1 * W31[c0 + 1];
  }
#pragma unroll
  for (int off = 32; off > 0; off >>= 1) {
    aa += __shfl_xor(aa, off);
    gg += __shfl_xor(gg, off);
  }
  if (lane == 0) {
    a3[wid] = aa + b3[0];
    g3[wid] = gg;
  }
}

__global__ void k_gather1(const unsigned* __restrict__ rowstart, const int2* __restrict__ er,
                          const float* __restrict__ dinv, const float* __restrict__ g3,
                          const float* __restrict__ a3, float* __restrict__ out, int N) {
  int n = blockIdx.x * blockDim.x + threadIdx.x;
  if (n >= N) return;
  unsigned s0 = rowstart[n], s1 = rowstart[n + 1];
  float a = 0.f, b = 0.f, c = 0.f, d = 0.f;
  unsigned e = s0;
  for (; e + 4 <= s1; e += 4) {
    int2 r0 = er[e], r1 = er[e + 1], r2 = er[e + 2], r3 = er[e + 3];
    float g0 = g3[r0.x], g1 = g3[r1.x], g2v = g3[r2.x], g3v = g3[r3.x];
    a += __int_as_float(r0.y) * g0;
    b += __int_as_float(r1.y) * g1;
    c += __int_as_float(r2.y) * g2v;
    d += __int_as_float(r3.y) * g3v;
  }
  for (; e < s1; ++e) {
    int2 r = er[e];
    a += __int_as_float(r.y) * g3[r.x];
  }
  out[n] = a3[n] - dinv[n] * ((a + b) + (c + d));
}

// ---------------- FUSED MFMA layer1+layer2 (phased accumulators) ------------
// Per wave (16 nodes), independent, no __syncthreads. Accumulator phases:
//   mm1 half0 (j 0-9, all s)  -> stage cols 0-159    (acc live: 10)
//   mm1 half1 (j 10-19)       -> stage cols 160-319
//   mm2 chunk0 (j 0-6, K=320) -> packed regs pk0[7]  (acc live: 7)
//   mm2 chunk1 (j 7-12)       -> packed regs pk1[6]
//   write out-stage [16][216], copy 6656B contiguous.
// W loaded ONCE total; stage re-read per chunk (cheap LDS). Peak live ~120
// regs < 168 cap -> the sched_barrier-pinned load groups fit without spill.
#define STG 324  // 648B row stride
__global__ __launch_bounds__(256, 3) void k_mm12_mfma(
    const unsigned short* __restrict__ xb, const uint4* __restrict__ W1f,
    const uint4* __restrict__ W2f, const float* __restrict__ b1pad,
    unsigned short* __restrict__ ga2b) {
  __shared__ unsigned short stage[4 * 16 * STG];  // 41.5 KB -> 3 blk/CU
  int tid = threadIdx.x;
  int lane = tid & 63, wv = tid >> 6, lr = lane & 15, g = lane >> 4;
  int n0 = blockIdx.x * 64 + wv * 16;
  unsigned short* ost = stage + wv * 16 * STG;

  // ---- mm1: two 10-j halves ----
  bf16x8 a1[4];
#pragma unroll
  for (int s = 0; s < 4; s++)
    a1[s] = *(const bf16x8*)(xb + (size_t)(n0 + lr) * 128 + s * 32 + g * 8);
#pragma unroll
  for (int half = 0; half < 2; half++) {
    f32x4 acc[10];
#pragma unroll
    for (int j = 0; j < 10; j++) acc[j] = (f32x4){0.f, 0.f, 0.f, 0.f};
#pragma unroll
    for (int s = 0; s < 4; s++) {
      bf16x8 w[10];
#pragma unroll
      for (int j = 0; j < 10; j++)
        w[j] = *(const bf16x8*)&W1f[(s * 20 + half * 10 + j) * 64 + lane];
      __builtin_amdgcn_sched_barrier(0);  // all 10 loads before any mfma
#pragma unroll
      for (int j = 0; j < 10; j++)
        acc[j] = __builtin_amdgcn_mfma_f32_16x16x32_bf16(w[j], a1[s], acc[j], 0, 0, 0);
    }
#pragma unroll
    for (int j = 0; j < 10; j++) {
      int c = half * 160 + j * 16 + g * 4;
      float4 bv = *(const float4*)(b1pad + c);
      unsigned lo = f2bf(fmaxf(acc[j][0] + bv.x, 0.f)) |
                    (f2bf(fmaxf(acc[j][1] + bv.y, 0.f)) << 16);
      unsigned hi = f2bf(fmaxf(acc[j][2] + bv.z, 0.f)) |
                    (f2bf(fmaxf(acc[j][3] + bv.w, 0.f)) << 16);
      uint2 pk; pk.x = lo; pk.y = hi;
      *(uint2*)(ost + lr * STG + c) = pk;
    }
  }

  // ---- mm2: chunk0 j 0-6, chunk1 j 7-12; outputs held packed in regs ----
  uint2 pk0[7], pk1[6];
  {
    f32x4 acc[7];
#pragma unroll
    for (int j = 0; j < 7; j++) acc[j] = (f32x4){0.f, 0.f, 0.f, 0.f};
#pragma unroll
    for (int s = 0; s < 10; s++) {
      bf16x8 a = *(const bf16x8*)(ost + lr * STG + s * 32 + g * 8);
      bf16x8 w[7];
#pragma unroll
      for (int j = 0; j < 7; j++) w[j] = *(const bf16x8*)&W2f[(s * 13 + j) * 64 + lane];
      __builtin_amdgcn_sched_barrier(0);
#pragma unroll
      for (int j = 0; j < 7; j++)
        acc[j] = __builtin_amdgcn_mfma_f32_16x16x32_bf16(w[j], a, acc[j], 0, 0, 0);
    }
#pragma unroll
    for (int j = 0; j < 7; j++) {
      pk0[j].x = f2bf(acc[j][0]) | (f2bf(acc[j][1]) << 16);
      pk0[j].y = f2bf(acc[j][2]) | (f2bf(acc[j][3]) << 16);
    }
  }
  {
    f32x4 acc[6];
#pragma unroll
    for (int j = 0; j < 6; j++) acc[j] = (f32x4){0.f, 0.f, 0.f, 0.f};
#pragma unroll
    for (int s = 0; s < 10; s++) {
      bf16x8 a = *(const bf16x8*)(ost + lr * STG + s * 32 + g * 8);
      bf16x8 w[6];
#pragma unroll
      for (int j = 0; j < 6; j++) w[j] = *(const bf16x8*)&W2f[(s * 13 + 7 + j) * 64 + lane];
      __builtin_amdgcn_sched_barrier(0);
#pragma unroll
      for (int j = 0; j < 6; j++)
        acc[j] = __builtin_amdgcn_mfma_f32_16x16x32_bf16(w[j], a, acc[j], 0, 0, 0);
    }
#pragma unroll
    for (int j = 0; j < 6; j++) {
      pk1[j].x = f2bf(acc[j][0]) | (f2bf(acc[j][1]) << 16);
      pk1[j].y = f2bf(acc[j][2]) | (f2bf(acc[j][3]) << 16);
    }
  }
  // out epilogue: all h1 stage reads are done; reuse stage as [16][216]
#pragma unroll
  for (int j = 0; j < 7; j++)
    *(uint2*)(ost + lr * 216 + j * 16 + g * 4) = pk0[j];
#pragma unroll
  for (int j = 0; j < 6; j++)
    *(uint2*)(ost + lr * 216 + (7 + j) * 16 + g * 4) = pk1[j];
  // wave tile rows n0..n0+15 x 208 cols = 6656 contiguous bytes (64B-aligned)
  uint4* gdst = (uint4*)(ga2b + (size_t)n0 * 208);
  for (int idx = lane; idx < 416; idx += 64) {
    int row = idx / 26, q = idx - row * 26;
    gdst[idx] = *(const uint4*)(ost + row * 216 + q * 8);
  }
}

// ---------------- launch ----------------
extern "C" void kernel_launch(void* const* d_in, const int* in_sizes, int n_in,
                              void* d_out, int out_size, void* d_ws, size_t ws_size,
                              hipStream_t stream) {
  const float* x  = (const float*)d_in[0];
  const int*   ei = (const int*)d_in[1];
  const float* W1 = (const float*)d_in[2];  // [2][58][300]
  const float* b1 = (const float*)d_in[3];
  const float* W2 = (const float*)d_in[4];  // [2][300][100]
  const float* b2 = (const float*)d_in[5];
  const float* W3 = (const float*)d_in[6];  // [2][100][1]
  const float* b3 = (const float*)d_in[7];
  float* out = (float*)d_out;

  const int N = in_sizes[0] / 58;            // 100000
  const int E = in_sizes[1] / 2;             // 800000
  const int NR = (N + 127) & ~127;           // 100096 (multiple of 64)
  const int NB = (N + 1023) / 1024;
  const int* src = ei;
  const int* dst = ei + E;

  char* ws = (char*)d_ws;
  size_t off = 0;
  auto alloc = [&](size_t bytes) -> void* {
    void* p = ws + off;
    off += (bytes + 255) & ~(size_t)255;
    return p;
  };
  unsigned* deg      = (unsigned*)alloc((size_t)2 * N * 4);
  unsigned* cnt      = deg + N;
  float*    dinv     = (float*)alloc((size_t)N * 4);
  unsigned* rowstart = (unsigned*)alloc((size_t)(N + 1) * 4);
  unsigned* rank     = (unsigned*)alloc((size_t)E * 4);
  unsigned* btot     = (unsigned*)alloc((size_t)256 * 4);
  int2*     er       = (int2*)alloc((size_t)E * 8);
  unsigned short* xb   = (unsigned short*)alloc((size_t)NR * 128 * 2);
  uint4*    W1f      = (uint4*)alloc((size_t)4 * 20 * 64 * 16);   // 80 KB
  uint4*    W2f      = (uint4*)alloc((size_t)10 * 13 * 64 * 16);  // 133 KB
  float*    b1pad    = (float*)alloc((size_t)320 * 4);
  unsigned short* ga2b = (unsigned short*)alloc((size_t)NR * 208 * 2);
  float* a3 = (float*)alloc((size_t)N * 4);
  float* g3 = (float*)alloc((size_t)N * 4);

  // --- CSR + dinv ---
  hipMemsetAsync(deg, 0, (size_t)2 * N * 4, stream);
  k_count<<<(E + 255) / 256, 256, 0, stream>>>(src, dst, deg, cnt, rank, E);
  k_dinv<<<(N + 255) / 256, 256, 0, stream>>>(deg, dinv, N);
  k_scan1<<<NB, 256, 0, stream>>>(cnt, btot, N);
  k_scan2<<<1, 256, 0, stream>>>(btot, rowstart, NB, N, E);
  k_scan3<<<NB, 256, 0, stream>>>(cnt, btot, rowstart, N);
  k_fill<<<(E + 255) / 256, 256, 0, stream>>>(src, dst, dinv, rowstart, rank, er, E);

  // --- preps ---
  k_prep_w1f<<<(4 * 20 * 64 + 255) / 256, 256, 0, stream>>>(W1, W1f);
  k_prep_w2f<<<(10 * 13 * 64 + 255) / 256, 256, 0, stream>>>(W2, W2f);
  k_prep_b1pad<<<2, 256, 0, stream>>>(b1, b1pad);
  k_prep_xb<<<((size_t)N * 64 + 255) / 256, 256, 0, stream>>>(x, xb, N);

  // --- layer 1+2 fused ---
  k_gather58<<<(N + 3) / 4, 256, 0, stream>>>(rowstart, er, dinv, xb, N);
  k_mm12_mfma<<<NR / 64, 256, 0, stream>>>(xb, W1f, W2f, b1pad, ga2b);
  k_gather_l2<<<(N + 3) / 4, 256, 0, stream>>>(rowstart, er, dinv, ga2b,
                                               b2, W3, W3 + 100, b3, a3, g3, N);

  // --- layer 3 ---
  k_gather1<<<(N + 255) / 256, 256, 0, stream>>>(rowstart, er, dinv, g3, a3, out, N);
}

// Round 15
// 271.012 us; speedup vs baseline: 1.4969x; 1.1252x over previous
//
#include <hip/hip_runtime.h>

// ---------------------------------------------------------------------------
// EMOGI ChebConv-K2 x3 : N=100000 nodes, E=800000 edges, dims 58->300->100->1
//   CSR by dst (count+rank / scan / fill-no-atomic) -> gathers.
//   xb  [NR][128] bf16 = [x | p1 | 0]       (p1 filled by gather58)
//   k_mm12: FUSED  h1 = relu([x|p1]@W1+b1) (wave-private LDS stage) ;
//           ga2b[NR][208] = h1 @ [W21|pad|W20|pad]
//   gather_l2: p2 = prop(g2); h2 = relu(a2+p2+b2) in-reg; a3,g3 = h2@W3 dots
//   gather1: out = a3 + prop(g3)
//
// R14 lesson: k_count is atomic-rate-bound (87us, VALU 0.25%, HBM 8%) --
// the rest of the machine is idle during it. And the gathers still pay two
// latency rounds per average node (4-wide+tail) with gather58 using only
// 29/64 lanes. This round: (1) preps folded INTO k_count as extra blocks
// (free overlap under the atomic floor); (2) gathers 8-wide masked-clamp
// (no tail; 8 er + 8 row loads in flight = one latency round per node);
// (3) gather58 packs 2 nodes per wave (lanes 0-31 / 32-63).
// ---------------------------------------------------------------------------

typedef short bf16x8 __attribute__((ext_vector_type(8)));
typedef float f32x4 __attribute__((ext_vector_type(4)));

__device__ __forceinline__ unsigned f2bf(float f) {  // RNE fp32->bf16 bits
  unsigned u = __float_as_uint(f);
  u += 0x7fff + ((u >> 16) & 1);
  return u >> 16;
}
__device__ __forceinline__ float bf2f(unsigned s) {
  return __uint_as_float(s << 16);
}

// ---------------- fused CSR-count + all preps ----------------
// blocks [0, EB): edge histograms (atomic-bound; issued first)
// blocks [EB, EB+XB): xb prep ; then 20 w1f ; 33 w2f ; 2 b1pad
__global__ void k_count_prep(
    const int* __restrict__ src, const int* __restrict__ dst,
    unsigned* __restrict__ deg, unsigned* __restrict__ cnt,
    unsigned* __restrict__ rank, int E, int EB,
    const float* __restrict__ x, unsigned short* __restrict__ xb, int N, int XB,
    const float* __restrict__ W1, uint4* __restrict__ W1f,
    const float* __restrict__ W2, uint4* __restrict__ W2f,
    const float* __restrict__ b1, float* __restrict__ b1pad) {
  int b = blockIdx.x, t = threadIdx.x;
  if (b < EB) {
    int i = b * 256 + t;
    if (i < E) {
      atomicAdd(&deg[src[i]], 1u);
      rank[i] = atomicAdd(&cnt[dst[i]], 1u);
    }
    return;
  }
  b -= EB;
  if (b < XB) {  // xb prep
    int idx = b * 256 + t;
    int n = idx >> 6, p = idx & 63;
    if (n >= N) return;
    int c = p * 2;
    if (c < 58) {
      unsigned lo = f2bf(x[(size_t)n * 58 + c]);
      unsigned hi = f2bf(x[(size_t)n * 58 + c + 1]);
      *(unsigned*)(xb + (size_t)n * 128 + c) = lo | (hi << 16);
    } else if (c >= 116) {
      *(unsigned*)(xb + (size_t)n * 128 + c) = 0;
    }
    return;
  }
  b -= XB;
  if (b < 20) {  // W1f fragment pack [s<4][j<20][lane<64][8 bf16]
    int idx = b * 256 + t;
    int lane = idx & 63, j = (idx >> 6) % 20, s = (idx >> 6) / 20;
    int lr = lane & 15, g = lane >> 4;
    int c = j * 16 + lr;
    unsigned short v[8];
#pragma unroll
    for (int i = 0; i < 8; i++) {
      int k = s * 32 + g * 8 + i;
      float f = 0.0f;
      if (c < 300 && k < 116)
        f = (k < 58) ? W1[k * 300 + c] : W1[17400 + (k - 58) * 300 + c];
      v[i] = (unsigned short)f2bf(f);
    }
    W1f[idx] = *(const uint4*)v;
    return;
  }
  b -= 20;
  if (b < 33) {  // W2f fragment pack [s<10][j<13][lane<64][8 bf16]
    int idx = b * 256 + t;
    if (idx >= 10 * 13 * 64) return;
    int lane = idx & 63, j = (idx >> 6) % 13, s = (idx >> 6) / 13;
    int lr = lane & 15, g = lane >> 4;
    int r = j * 16 + lr;
    unsigned short v[8];
#pragma unroll
    for (int i = 0; i < 8; i++) {
      int k = s * 32 + g * 8 + i;
      float f = 0.0f;
      if (k < 300) {
        if (r < 100) f = W2[30000 + k * 100 + r];
        else if (r >= 104 && r < 204) f = W2[k * 100 + (r - 104)];
      }
      v[i] = (unsigned short)f2bf(f);
    }
    W2f[idx] = *(const uint4*)v;
    return;
  }
  b -= 33;
  {  // b1pad (2 blocks)
    int idx = b * 256 + t;
    if (idx < 320) b1pad[idx] = (idx < 300) ? b1[idx] : 0.0f;
  }
}

__global__ void k_dinv(const unsigned* __restrict__ deg, float* __restrict__ dinv, int N) {
  int i = blockIdx.x * blockDim.x + threadIdx.x;
  if (i < N) {
    unsigned d = deg[i];
    dinv[i] = d ? rsqrtf((float)d) : 0.0f;
  }
}

__global__ __launch_bounds__(256) void k_scan1(const unsigned* __restrict__ cnt,
                                               unsigned* __restrict__ btot, int N) {
  __shared__ unsigned s[256];
  int b = blockIdx.x, t = threadIdx.x;
  int base = b * 1024;
  unsigned sum = 0;
  for (int i = t; i < 1024; i += 256) {
    int idx = base + i;
    sum += (idx < N) ? cnt[idx] : 0u;
  }
  s[t] = sum;
  __syncthreads();
  for (int off = 128; off > 0; off >>= 1) {
    if (t < off) s[t] += s[t + off];
    __syncthreads();
  }
  if (t == 0) btot[b] = s[0];
}

__global__ __launch_bounds__(256) void k_scan2(unsigned* __restrict__ btot,
                                               unsigned* __restrict__ rowstart,
                                               int NB, int N, int E) {
  __shared__ unsigned s[256];
  int t = threadIdx.x;
  s[t] = (t < NB) ? btot[t] : 0u;
  __syncthreads();
  if (t == 0) {
    unsigned acc = 0;
    for (int i = 0; i < NB; i++) { unsigned v = s[i]; s[i] = acc; acc += v; }
  }
  __syncthreads();
  if (t < NB) btot[t] = s[t];
  if (t == 0) rowstart[N] = (unsigned)E;
}

__global__ __launch_bounds__(256) void k_scan3(const unsigned* __restrict__ cnt,
                                               const unsigned* __restrict__ btot,
                                               unsigned* __restrict__ rowstart, int N) {
  __shared__ unsigned ssum[256];
  int b = blockIdx.x, t = threadIdx.x;
  int base = b * 1024 + t * 4;
  unsigned v0 = 0, v1 = 0, v2 = 0, v3 = 0;
  if (base + 0 < N) v0 = cnt[base + 0];
  if (base + 1 < N) v1 = cnt[base + 1];
  if (base + 2 < N) v2 = cnt[base + 2];
  if (base + 3 < N) v3 = cnt[base + 3];
  ssum[t] = v0 + v1 + v2 + v3;
  __syncthreads();
  for (int off = 1; off < 256; off <<= 1) {
    unsigned add = (t >= off) ? ssum[t - off] : 0u;
    __syncthreads();
    ssum[t] += add;
    __syncthreads();
  }
  unsigned texcl = ((t == 0) ? 0u : ssum[t - 1]) + btot[b];
  unsigned r0 = texcl, r1 = r0 + v0, r2 = r1 + v1, r3 = r2 + v2;
  if (base + 0 < N) rowstart[base + 0] = r0;
  if (base + 1 < N) rowstart[base + 1] = r1;
  if (base + 2 < N) rowstart[base + 2] = r2;
  if (base + 3 < N) rowstart[base + 3] = r3;
}

// fill without atomics: position = rowstart[dst] + rank (from k_count_prep)
__global__ void k_fill(const int* __restrict__ src, const int* __restrict__ dst,
                       const float* __restrict__ dinv, const unsigned* __restrict__ rowstart,
                       const unsigned* __restrict__ rank, int2* __restrict__ er, int E) {
  int e = blockIdx.x * blockDim.x + threadIdx.x;
  if (e >= E) return;
  int s = src[e], d = dst[e];
  er[rowstart[d] + rank[e]] = make_int2(s, __float_as_int(dinv[s]));
}

// ---------------- gathers (8-wide masked MLP) ----------------
// p1 = prop(x): 2 nodes per wave (lanes 0-31 node A, 32-63 node B).
__global__ __launch_bounds__(256) void k_gather58(
    const unsigned* __restrict__ rowstart, const int2* __restrict__ er,
    const float* __restrict__ dinv, unsigned short* __restrict__ xb, int N) {
  int pair = (blockIdx.x * blockDim.x + threadIdx.x) >> 6;
  int lane = threadIdx.x & 63;
  int wid = pair * 2 + (lane >> 5);
  int c0 = (lane & 31) * 2;
  if (wid >= N || c0 >= 58) return;
  unsigned s0 = rowstart[wid], s1 = rowstart[wid + 1];
  float a0[8], a1[8];
#pragma unroll
  for (int k = 0; k < 8; k++) { a0[k] = 0.f; a1[k] = 0.f; }
  for (unsigned e = s0; e < s1; e += 8) {
    int2 r[8];
#pragma unroll
    for (int k = 0; k < 8; k++) {
      unsigned idx = e + k;
      r[k] = er[idx < s1 ? idx : s1 - 1];
    }
    unsigned v[8];
#pragma unroll
    for (int k = 0; k < 8; k++)
      v[k] = *(const unsigned*)(xb + (size_t)r[k].x * 128 + c0);
#pragma unroll
    for (int k = 0; k < 8; k++) {
      float w = (e + k < s1) ? __int_as_float(r[k].y) : 0.f;
      a0[k] += w * bf2f(v[k] & 0xffffu);
      a1[k] += w * bf2f(v[k] >> 16);
    }
  }
  float dd = -dinv[wid];
  float p0 = dd * (((a0[0] + a0[1]) + (a0[2] + a0[3])) + ((a0[4] + a0[5]) + (a0[6] + a0[7])));
  float p1 = dd * (((a1[0] + a1[1]) + (a1[2] + a1[3])) + ((a1[4] + a1[5]) + (a1[6] + a1[7])));
  *(unsigned*)(xb + (size_t)wid * 128 + 58 + c0) = f2bf(p0) | (f2bf(p1) << 16);
}

// layer2 tail fused: p2 = prop(g2); h2 = relu(a2+p2+b2); a3,g3 = h2@W30/W31
__global__ __launch_bounds__(256) void k_gather_l2(
    const unsigned* __restrict__ rowstart, const int2* __restrict__ er,
    const float* __restrict__ dinv, const unsigned short* __restrict__ ga2b,
    const float* __restrict__ b2, const float* __restrict__ W30,
    const float* __restrict__ W31, const float* __restrict__ b3,
    float* __restrict__ a3, float* __restrict__ g3, int N) {
  int wid = (blockIdx.x * blockDim.x + threadIdx.x) >> 6;
  if (wid >= N) return;
  int lane = threadIdx.x & 63;
  int c0 = lane * 2;
  bool act = c0 < 100;
  unsigned s0 = rowstart[wid], s1 = rowstart[wid + 1];
  float aa = 0.f, gg = 0.f;
  if (act) {
    float a0[8], a1[8];
#pragma unroll
    for (int k = 0; k < 8; k++) { a0[k] = 0.f; a1[k] = 0.f; }
    for (unsigned e = s0; e < s1; e += 8) {
      int2 r[8];
#pragma unroll
      for (int k = 0; k < 8; k++) {
        unsigned idx = e + k;
        r[k] = er[idx < s1 ? idx : s1 - 1];
      }
      unsigned v[8];
#pragma unroll
      for (int k = 0; k < 8; k++)
        v[k] = *(const unsigned*)(ga2b + (size_t)r[k].x * 208 + c0);
#pragma unroll
      for (int k = 0; k < 8; k++) {
        float w = (e + k < s1) ? __int_as_float(r[k].y) : 0.f;
        a0[k] += w * bf2f(v[k] & 0xffffu);
        a1[k] += w * bf2f(v[k] >> 16);
      }
    }
    float dd = -dinv[wid];
    float p0 = dd * (((a0[0] + a0[1]) + (a0[2] + a0[3])) + ((a0[4] + a0[5]) + (a0[6] + a0[7])));
    float p1 = dd * (((a1[0] + a1[1]) + (a1[2] + a1[3])) + ((a1[4] + a1[5]) + (a1[6] + a1[7])));
    unsigned av = *(const unsigned*)(ga2b + (size_t)wid * 208 + 104 + c0);
    float h0 = fmaxf(bf2f(av & 0xffffu) + p0 + b2[c0], 0.f);
    float h1 = fmaxf(bf2f(av >> 16) + p1 + b2[c0 + 1], 0.f);
    aa = h0 * W30[c0] + h1 * W30[c0 + 1];
    gg = h0 * W31[c0] + h1 * W31[c0 + 1];
  }
#pragma unroll
  for (int off = 32; off > 0; off >>= 1) {
    aa += __shfl_xor(aa, off);
    gg += __shfl_xor(gg, off);
  }
  if (lane == 0) {
    a3[wid] = aa + b3[0];
    g3[wid] = gg;
  }
}

// out = a3 + prop(g3), thread/node, 8-wide masked
__global__ void k_gather1(const unsigned* __restrict__ rowstart, const int2* __restrict__ er,
                          const float* __restrict__ dinv, const float* __restrict__ g3,
                          const float* __restrict__ a3, float* __restrict__ out, int N) {
  int n = blockIdx.x * blockDim.x + threadIdx.x;
  if (n >= N) return;
  unsigned s0 = rowstart[n], s1 = rowstart[n + 1];
  float a[8];
#pragma unroll
  for (int k = 0; k < 8; k++) a[k] = 0.f;
  for (unsigned e = s0; e < s1; e += 8) {
    int2 r[8];
#pragma unroll
    for (int k = 0; k < 8; k++) {
      unsigned idx = e + k;
      r[k] = er[idx < s1 ? idx : s1 - 1];
    }
    float gv[8];
#pragma unroll
    for (int k = 0; k < 8; k++) gv[k] = g3[r[k].x];
#pragma unroll
    for (int k = 0; k < 8; k++) {
      float w = (e + k < s1) ? __int_as_float(r[k].y) : 0.f;
      a[k] += w * gv[k];
    }
  }
  float sum = ((a[0] + a[1]) + (a[2] + a[3])) + ((a[4] + a[5]) + (a[6] + a[7]));
  out[n] = a3[n] - dinv[n] * sum;
}

// ---------------- FUSED MFMA layer1+layer2 (phased accumulators) ------------
#define STG 324  // 648B row stride
__global__ __launch_bounds__(256, 3) void k_mm12_mfma(
    const unsigned short* __restrict__ xb, const uint4* __restrict__ W1f,
    const uint4* __restrict__ W2f, const float* __restrict__ b1pad,
    unsigned short* __restrict__ ga2b) {
  __shared__ unsigned short stage[4 * 16 * STG];  // 41.5 KB -> 3 blk/CU
  int tid = threadIdx.x;
  int lane = tid & 63, wv = tid >> 6, lr = lane & 15, g = lane >> 4;
  int n0 = blockIdx.x * 64 + wv * 16;
  unsigned short* ost = stage + wv * 16 * STG;

  // ---- mm1: two 10-j halves ----
  bf16x8 a1[4];
#pragma unroll
  for (int s = 0; s < 4; s++)
    a1[s] = *(const bf16x8*)(xb + (size_t)(n0 + lr) * 128 + s * 32 + g * 8);
#pragma unroll
  for (int half = 0; half < 2; half++) {
    f32x4 acc[10];
#pragma unroll
    for (int j = 0; j < 10; j++) acc[j] = (f32x4){0.f, 0.f, 0.f, 0.f};
#pragma unroll
    for (int s = 0; s < 4; s++) {
      bf16x8 w[10];
#pragma unroll
      for (int j = 0; j < 10; j++)
        w[j] = *(const bf16x8*)&W1f[(s * 20 + half * 10 + j) * 64 + lane];
      __builtin_amdgcn_sched_barrier(0);  // all 10 loads before any mfma
#pragma unroll
      for (int j = 0; j < 10; j++)
        acc[j] = __builtin_amdgcn_mfma_f32_16x16x32_bf16(w[j], a1[s], acc[j], 0, 0, 0);
    }
#pragma unroll
    for (int j = 0; j < 10; j++) {
      int c = half * 160 + j * 16 + g * 4;
      float4 bv = *(const float4*)(b1pad + c);
      unsigned lo = f2bf(fmaxf(acc[j][0] + bv.x, 0.f)) |
                    (f2bf(fmaxf(acc[j][1] + bv.y, 0.f)) << 16);
      unsigned hi = f2bf(fmaxf(acc[j][2] + bv.z, 0.f)) |
                    (f2bf(fmaxf(acc[j][3] + bv.w, 0.f)) << 16);
      uint2 pk; pk.x = lo; pk.y = hi;
      *(uint2*)(ost + lr * STG + c) = pk;
    }
  }

  // ---- mm2: chunk0 j 0-6, chunk1 j 7-12; outputs held packed in regs ----
  uint2 pk0[7], pk1[6];
  {
    f32x4 acc[7];
#pragma unroll
    for (int j = 0; j < 7; j++) acc[j] = (f32x4){0.f, 0.f, 0.f, 0.f};
#pragma unroll
    for (int s = 0; s < 10; s++) {
      bf16x8 a = *(const bf16x8*)(ost + lr * STG + s * 32 + g * 8);
      bf16x8 w[7];
#pragma unroll
      for (int j = 0; j < 7; j++) w[j] = *(const bf16x8*)&W2f[(s * 13 + j) * 64 + lane];
      __builtin_amdgcn_sched_barrier(0);
#pragma unroll
      for (int j = 0; j < 7; j++)
        acc[j] = __builtin_amdgcn_mfma_f32_16x16x32_bf16(w[j], a, acc[j], 0, 0, 0);
    }
#pragma unroll
    for (int j = 0; j < 7; j++) {
      pk0[j].x = f2bf(acc[j][0]) | (f2bf(acc[j][1]) << 16);
      pk0[j].y = f2bf(acc[j][2]) | (f2bf(acc[j][3]) << 16);
    }
  }
  {
    f32x4 acc[6];
#pragma unroll
    for (int j = 0; j < 6; j++) acc[j] = (f32x4){0.f, 0.f, 0.f, 0.f};
#pragma unroll
    for (int s = 0; s < 10; s++) {
      bf16x8 a = *(const bf16x8*)(ost + lr * STG + s * 32 + g * 8);
      bf16x8 w[6];
#pragma unroll
      for (int j = 0; j < 6; j++) w[j] = *(const bf16x8*)&W2f[(s * 13 + 7 + j) * 64 + lane];
      __builtin_amdgcn_sched_barrier(0);
#pragma unroll
      for (int j = 0; j < 6; j++)
        acc[j] = __builtin_amdgcn_mfma_f32_16x16x32_bf16(w[j], a, acc[j], 0, 0, 0);
    }
#pragma unroll
    for (int j = 0; j < 6; j++) {
      pk1[j].x = f2bf(acc[j][0]) | (f2bf(acc[j][1]) << 16);
      pk1[j].y = f2bf(acc[j][2]) | (f2bf(acc[j][3]) << 16);
    }
  }
  // out epilogue: all h1 stage reads are done; reuse stage as [16][216]
#pragma unroll
  for (int j = 0; j < 7; j++)
    *(uint2*)(ost + lr * 216 + j * 16 + g * 4) = pk0[j];
#pragma unroll
  for (int j = 0; j < 6; j++)
    *(uint2*)(ost + lr * 216 + (7 + j) * 16 + g * 4) = pk1[j];
  // wave tile rows n0..n0+15 x 208 cols = 6656 contiguous bytes (64B-aligned)
  uint4* gdst = (uint4*)(ga2b + (size_t)n0 * 208);
  for (int idx = lane; idx < 416; idx += 64) {
    int row = idx / 26, q = idx - row * 26;
    gdst[idx] = *(const uint4*)(ost + row * 216 + q * 8);
  }
}

// ---------------- launch ----------------
extern "C" void kernel_launch(void* const* d_in, const int* in_sizes, int n_in,
                              void* d_out, int out_size, void* d_ws, size_t ws_size,
                              hipStream_t stream) {
  const float* x  = (const float*)d_in[0];
  const int*   ei = (const int*)d_in[1];
  const float* W1 = (const float*)d_in[2];  // [2][58][300]
  const float* b1 = (const float*)d_in[3];
  const float* W2 = (const float*)d_in[4];  // [2][300][100]
  const float* b2 = (const float*)d_in[5];
  const float* W3 = (const float*)d_in[6];  // [2][100][1]
  const float* b3 = (const float*)d_in[7];
  float* out = (float*)d_out;

  const int N = in_sizes[0] / 58;            // 100000
  const int E = in_sizes[1] / 2;             // 800000
  const int NR = (N + 127) & ~127;           // 100096 (multiple of 64)
  const int NB = (N + 1023) / 1024;
  const int* src = ei;
  const int* dst = ei + E;

  char* ws = (char*)d_ws;
  size_t off = 0;
  auto alloc = [&](size_t bytes) -> void* {
    void* p = ws + off;
    off += (bytes + 255) & ~(size_t)255;
    return p;
  };
  unsigned* deg      = (unsigned*)alloc((size_t)2 * N * 4);
  unsigned* cnt      = deg + N;
  float*    dinv     = (float*)alloc((size_t)N * 4);
  unsigned* rowstart = (unsigned*)alloc((size_t)(N + 1) * 4);
  unsigned* rank     = (unsigned*)alloc((size_t)E * 4);
  unsigned* btot     = (unsigned*)alloc((size_t)256 * 4);
  int2*     er       = (int2*)alloc((size_t)E * 8);
  unsigned short* xb   = (unsigned short*)alloc((size_t)NR * 128 * 2);
  uint4*    W1f      = (uint4*)alloc((size_t)4 * 20 * 64 * 16);   // 80 KB
  uint4*    W2f      = (uint4*)alloc((size_t)10 * 13 * 64 * 16);  // 133 KB
  float*    b1pad    = (float*)alloc((size_t)320 * 4);
  unsigned short* ga2b = (unsigned short*)alloc((size_t)NR * 208 * 2);
  float* a3 = (float*)alloc((size_t)N * 4);
  float* g3 = (float*)alloc((size_t)N * 4);

  const int EB = (E + 255) / 256;            // 3125 edge blocks
  const int XB = ((size_t)N * 64 + 255) / 256;  // 25000 xb blocks

  // --- CSR count + ALL preps fused (preps ride under the atomic floor) ---
  hipMemsetAsync(deg, 0, (size_t)2 * N * 4, stream);
  k_count_prep<<<EB + XB + 20 + 33 + 2, 256, 0, stream>>>(
      src, dst, deg, cnt, rank, E, EB, x, xb, N, XB, W1, W1f, W2, W2f, b1, b1pad);
  k_dinv<<<(N + 255) / 256, 256, 0, stream>>>(deg, dinv, N);
  k_scan1<<<NB, 256, 0, stream>>>(cnt, btot, N);
  k_scan2<<<1, 256, 0, stream>>>(btot, rowstart, NB, N, E);
  k_scan3<<<NB, 256, 0, stream>>>(cnt, btot, rowstart, N);
  k_fill<<<(E + 255) / 256, 256, 0, stream>>>(src, dst, dinv, rowstart, rank, er, E);

  // --- layer 1+2 fused ---
  k_gather58<<<((N + 1) / 2 * 64 + 255) / 256, 256, 0, stream>>>(rowstart, er, dinv, xb, N);
  k_mm12_mfma<<<NR / 64, 256, 0, stream>>>(xb, W1f, W2f, b1pad, ga2b);
  k_gather_l2<<<(N + 3) / 4, 256, 0, stream>>>(rowstart, er, dinv, ga2b,
                                               b2, W3, W3 + 100, b3, a3, g3, N);

  // --- layer 3 ---
  k_gather1<<<(N + 255) / 256, 256, 0, stream>>>(rowstart, er, dinv, g3, a3, out, N);
}

// Round 16
// 265.612 us; speedup vs baseline: 1.5274x; 1.0203x over previous
//
#include <hip/hip_runtime.h>

// ---------------------------------------------------------------------------
// EMOGI ChebConv-K2 x3 : N=100000 nodes, E=800000 edges, dims 58->300->100->1
//   CSR by dst (count+rank / scan / fill-no-atomic) -> gathers.
//   xb  [NR][128] bf16 = [x | p1 | 0]       (p1 filled by gather58)
//   k_mm12: FUSED  h1 = relu([x|p1]@W1+b1) (wave-private LDS stage) ;
//           ga2b[NR][208] = h1 @ [W21|pad|W20|pad]
//   gather_l2: p2 = prop(g2); h2 = relu(a2+p2+b2) in-reg; a3,g3 = h2@W3 dots
//   gather1: out = a3 + prop(g3)
//
// R15 lesson: k_count_prep sits on the device-atomic floor (~87us). The
// remaining soft target is mm12: each 16-node wave privately streams 213KB
// of W from L2 (1.33GB total = 39us floor). This round: 32-NODE WAVES in
// 128-thread blocks -- same 41.5KB LDS (3 blk/CU) but only 2 waves/SIMD ->
// VGPR cap 256 (vs 168), so doubled acc phases + pinned W groups fit.
// W traffic halves (0.67GB ~19us floor); each W frag feeds 2 mfmas.
// ---------------------------------------------------------------------------

typedef short bf16x8 __attribute__((ext_vector_type(8)));
typedef float f32x4 __attribute__((ext_vector_type(4)));

__device__ __forceinline__ unsigned f2bf(float f) {  // RNE fp32->bf16 bits
  unsigned u = __float_as_uint(f);
  u += 0x7fff + ((u >> 16) & 1);
  return u >> 16;
}
__device__ __forceinline__ float bf2f(unsigned s) {
  return __uint_as_float(s << 16);
}

// ---------------- fused CSR-count + all preps ----------------
__global__ void k_count_prep(
    const int* __restrict__ src, const int* __restrict__ dst,
    unsigned* __restrict__ deg, unsigned* __restrict__ cnt,
    unsigned* __restrict__ rank, int E, int EB,
    const float* __restrict__ x, unsigned short* __restrict__ xb, int N, int XB,
    const float* __restrict__ W1, uint4* __restrict__ W1f,
    const float* __restrict__ W2, uint4* __restrict__ W2f,
    const float* __restrict__ b1, float* __restrict__ b1pad) {
  int b = blockIdx.x, t = threadIdx.x;
  if (b < EB) {
    int i = b * 256 + t;
    if (i < E) {
      atomicAdd(&deg[src[i]], 1u);
      rank[i] = atomicAdd(&cnt[dst[i]], 1u);
    }
    return;
  }
  b -= EB;
  if (b < XB) {  // xb prep
    int idx = b * 256 + t;
    int n = idx >> 6, p = idx & 63;
    if (n >= N) return;
    int c = p * 2;
    if (c < 58) {
      unsigned lo = f2bf(x[(size_t)n * 58 + c]);
      unsigned hi = f2bf(x[(size_t)n * 58 + c + 1]);
      *(unsigned*)(xb + (size_t)n * 128 + c) = lo | (hi << 16);
    } else if (c >= 116) {
      *(unsigned*)(xb + (size_t)n * 128 + c) = 0;
    }
    return;
  }
  b -= XB;
  if (b < 20) {  // W1f fragment pack [s<4][j<20][lane<64][8 bf16]
    int idx = b * 256 + t;
    int lane = idx & 63, j = (idx >> 6) % 20, s = (idx >> 6) / 20;
    int lr = lane & 15, g = lane >> 4;
    int c = j * 16 + lr;
    unsigned short v[8];
#pragma unroll
    for (int i = 0; i < 8; i++) {
      int k = s * 32 + g * 8 + i;
      float f = 0.0f;
      if (c < 300 && k < 116)
        f = (k < 58) ? W1[k * 300 + c] : W1[17400 + (k - 58) * 300 + c];
      v[i] = (unsigned short)f2bf(f);
    }
    W1f[idx] = *(const uint4*)v;
    return;
  }
  b -= 20;
  if (b < 33) {  // W2f fragment pack [s<10][j<13][lane<64][8 bf16]
    int idx = b * 256 + t;
    if (idx >= 10 * 13 * 64) return;
    int lane = idx & 63, j = (idx >> 6) % 13, s = (idx >> 6) / 13;
    int lr = lane & 15, g = lane >> 4;
    int r = j * 16 + lr;
    unsigned short v[8];
#pragma unroll
    for (int i = 0; i < 8; i++) {
      int k = s * 32 + g * 8 + i;
      float f = 0.0f;
      if (k < 300) {
        if (r < 100) f = W2[30000 + k * 100 + r];
        else if (r >= 104 && r < 204) f = W2[k * 100 + (r - 104)];
      }
      v[i] = (unsigned short)f2bf(f);
    }
    W2f[idx] = *(const uint4*)v;
    return;
  }
  b -= 33;
  {  // b1pad (2 blocks)
    int idx = b * 256 + t;
    if (idx < 320) b1pad[idx] = (idx < 300) ? b1[idx] : 0.0f;
  }
}

__global__ void k_dinv(const unsigned* __restrict__ deg, float* __restrict__ dinv, int N) {
  int i = blockIdx.x * blockDim.x + threadIdx.x;
  if (i < N) {
    unsigned d = deg[i];
    dinv[i] = d ? rsqrtf((float)d) : 0.0f;
  }
}

__global__ __launch_bounds__(256) void k_scan1(const unsigned* __restrict__ cnt,
                                               unsigned* __restrict__ btot, int N) {
  __shared__ unsigned s[256];
  int b = blockIdx.x, t = threadIdx.x;
  int base = b * 1024;
  unsigned sum = 0;
  for (int i = t; i < 1024; i += 256) {
    int idx = base + i;
    sum += (idx < N) ? cnt[idx] : 0u;
  }
  s[t] = sum;
  __syncthreads();
  for (int off = 128; off > 0; off >>= 1) {
    if (t < off) s[t] += s[t + off];
    __syncthreads();
  }
  if (t == 0) btot[b] = s[0];
}

__global__ __launch_bounds__(256) void k_scan2(unsigned* __restrict__ btot,
                                               unsigned* __restrict__ rowstart,
                                               int NB, int N, int E) {
  __shared__ unsigned s[256];
  int t = threadIdx.x;
  s[t] = (t < NB) ? btot[t] : 0u;
  __syncthreads();
  if (t == 0) {
    unsigned acc = 0;
    for (int i = 0; i < NB; i++) { unsigned v = s[i]; s[i] = acc; acc += v; }
  }
  __syncthreads();
  if (t < NB) btot[t] = s[t];
  if (t == 0) rowstart[N] = (unsigned)E;
}

__global__ __launch_bounds__(256) void k_scan3(const unsigned* __restrict__ cnt,
                                               const unsigned* __restrict__ btot,
                                               unsigned* __restrict__ rowstart, int N) {
  __shared__ unsigned ssum[256];
  int b = blockIdx.x, t = threadIdx.x;
  int base = b * 1024 + t * 4;
  unsigned v0 = 0, v1 = 0, v2 = 0, v3 = 0;
  if (base + 0 < N) v0 = cnt[base + 0];
  if (base + 1 < N) v1 = cnt[base + 1];
  if (base + 2 < N) v2 = cnt[base + 2];
  if (base + 3 < N) v3 = cnt[base + 3];
  ssum[t] = v0 + v1 + v2 + v3;
  __syncthreads();
  for (int off = 1; off < 256; off <<= 1) {
    unsigned add = (t >= off) ? ssum[t - off] : 0u;
    __syncthreads();
    ssum[t] += add;
    __syncthreads();
  }
  unsigned texcl = ((t == 0) ? 0u : ssum[t - 1]) + btot[b];
  unsigned r0 = texcl, r1 = r0 + v0, r2 = r1 + v1, r3 = r2 + v2;
  if (base + 0 < N) rowstart[base + 0] = r0;
  if (base + 1 < N) rowstart[base + 1] = r1;
  if (base + 2 < N) rowstart[base + 2] = r2;
  if (base + 3 < N) rowstart[base + 3] = r3;
}

// fill without atomics: position = rowstart[dst] + rank (from k_count_prep)
__global__ void k_fill(const int* __restrict__ src, const int* __restrict__ dst,
                       const float* __restrict__ dinv, const unsigned* __restrict__ rowstart,
                       const unsigned* __restrict__ rank, int2* __restrict__ er, int E) {
  int e = blockIdx.x * blockDim.x + threadIdx.x;
  if (e >= E) return;
  int s = src[e], d = dst[e];
  er[rowstart[d] + rank[e]] = make_int2(s, __float_as_int(dinv[s]));
}

// ---------------- gathers (8-wide masked MLP) ----------------
// p1 = prop(x): 2 nodes per wave (lanes 0-31 node A, 32-63 node B).
__global__ __launch_bounds__(256) void k_gather58(
    const unsigned* __restrict__ rowstart, const int2* __restrict__ er,
    const float* __restrict__ dinv, unsigned short* __restrict__ xb, int N) {
  int pair = (blockIdx.x * blockDim.x + threadIdx.x) >> 6;
  int lane = threadIdx.x & 63;
  int wid = pair * 2 + (lane >> 5);
  int c0 = (lane & 31) * 2;
  if (wid >= N || c0 >= 58) return;
  unsigned s0 = rowstart[wid], s1 = rowstart[wid + 1];
  float a0[8], a1[8];
#pragma unroll
  for (int k = 0; k < 8; k++) { a0[k] = 0.f; a1[k] = 0.f; }
  for (unsigned e = s0; e < s1; e += 8) {
    int2 r[8];
#pragma unroll
    for (int k = 0; k < 8; k++) {
      unsigned idx = e + k;
      r[k] = er[idx < s1 ? idx : s1 - 1];
    }
    unsigned v[8];
#pragma unroll
    for (int k = 0; k < 8; k++)
      v[k] = *(const unsigned*)(xb + (size_t)r[k].x * 128 + c0);
#pragma unroll
    for (int k = 0; k < 8; k++) {
      float w = (e + k < s1) ? __int_as_float(r[k].y) : 0.f;
      a0[k] += w * bf2f(v[k] & 0xffffu);
      a1[k] += w * bf2f(v[k] >> 16);
    }
  }
  float dd = -dinv[wid];
  float p0 = dd * (((a0[0] + a0[1]) + (a0[2] + a0[3])) + ((a0[4] + a0[5]) + (a0[6] + a0[7])));
  float p1 = dd * (((a1[0] + a1[1]) + (a1[2] + a1[3])) + ((a1[4] + a1[5]) + (a1[6] + a1[7])));
  *(unsigned*)(xb + (size_t)wid * 128 + 58 + c0) = f2bf(p0) | (f2bf(p1) << 16);
}

// layer2 tail fused: p2 = prop(g2); h2 = relu(a2+p2+b2); a3,g3 = h2@W30/W31
__global__ __launch_bounds__(256) void k_gather_l2(
    const unsigned* __restrict__ rowstart, const int2* __restrict__ er,
    const float* __restrict__ dinv, const unsigned short* __restrict__ ga2b,
    const float* __restrict__ b2, const float* __restrict__ W30,
    const float* __restrict__ W31, const float* __restrict__ b3,
    float* __restrict__ a3, float* __restrict__ g3, int N) {
  int wid = (blockIdx.x * blockDim.x + threadIdx.x) >> 6;
  if (wid >= N) return;
  int lane = threadIdx.x & 63;
  int c0 = lane * 2;
  bool act = c0 < 100;
  unsigned s0 = rowstart[wid], s1 = rowstart[wid + 1];
  float aa = 0.f, gg = 0.f;
  if (act) {
    float a0[8], a1[8];
#pragma unroll
    for (int k = 0; k < 8; k++) { a0[k] = 0.f; a1[k] = 0.f; }
    for (unsigned e = s0; e < s1; e += 8) {
      int2 r[8];
#pragma unroll
      for (int k = 0; k < 8; k++) {
        unsigned idx = e + k;
        r[k] = er[idx < s1 ? idx : s1 - 1];
      }
      unsigned v[8];
#pragma unroll
      for (int k = 0; k < 8; k++)
        v[k] = *(const unsigned*)(ga2b + (size_t)r[k].x * 208 + c0);
#pragma unroll
      for (int k = 0; k < 8; k++) {
        float w = (e + k < s1) ? __int_as_float(r[k].y) : 0.f;
        a0[k] += w * bf2f(v[k] & 0xffffu);
        a1[k] += w * bf2f(v[k] >> 16);
      }
    }
    float dd = -dinv[wid];
    float p0 = dd * (((a0[0] + a0[1]) + (a0[2] + a0[3])) + ((a0[4] + a0[5]) + (a0[6] + a0[7])));
    float p1 = dd * (((a1[0] + a1[1]) + (a1[2] + a1[3])) + ((a1[4] + a1[5]) + (a1[6] + a1[7])));
    unsigned av = *(const unsigned*)(ga2b + (size_t)wid * 208 + 104 + c0);
    float h0 = fmaxf(bf2f(av & 0xffffu) + p0 + b2[c0], 0.f);
    float h1 = fmaxf(bf2f(av >> 16) + p1 + b2[c0 + 1], 0.f);
    aa = h0 * W30[c0] + h1 * W30[c0 + 1];
    gg = h0 * W31[c0] + h1 * W31[c0 + 1];
  }
#pragma unroll
  for (int off = 32; off > 0; off >>= 1) {
    aa += __shfl_xor(aa, off);
    gg += __shfl_xor(gg, off);
  }
  if (lane == 0) {
    a3[wid] = aa + b3[0];
    g3[wid] = gg;
  }
}

// out = a3 + prop(g3), thread/node, 8-wide masked
__global__ void k_gather1(const unsigned* __restrict__ rowstart, const int2* __restrict__ er,
                          const float* __restrict__ dinv, const float* __restrict__ g3,
                          const float* __restrict__ a3, float* __restrict__ out, int N) {
  int n = blockIdx.x * blockDim.x + threadIdx.x;
  if (n >= N) return;
  unsigned s0 = rowstart[n], s1 = rowstart[n + 1];
  float a[8];
#pragma unroll
  for (int k = 0; k < 8; k++) a[k] = 0.f;
  for (unsigned e = s0; e < s1; e += 8) {
    int2 r[8];
#pragma unroll
    for (int k = 0; k < 8; k++) {
      unsigned idx = e + k;
      r[k] = er[idx < s1 ? idx : s1 - 1];
    }
    float gv[8];
#pragma unroll
    for (int k = 0; k < 8; k++) gv[k] = g3[r[k].x];
#pragma unroll
    for (int k = 0; k < 8; k++) {
      float w = (e + k < s1) ? __int_as_float(r[k].y) : 0.f;
      a[k] += w * gv[k];
    }
  }
  float sum = ((a[0] + a[1]) + (a[2] + a[3])) + ((a[4] + a[5]) + (a[6] + a[7]));
  out[n] = a3[n] - dinv[n] * sum;
}

// ---------------- FUSED MFMA layer1+layer2 (32-node waves) ------------------
// 128-thread blocks (2 waves), each wave owns 32 nodes as two 16-row
// sub-tiles T0/T1 sharing every W fragment (1 W load : 2 mfma). LDS stage
// 2 x 32 x STG x 2B = 41.5KB -> 3 blk/CU; 2 waves/SIMD -> VGPR cap 256,
// fits phased acc (80) + pinned W group (40) + A frags (32) without spill.
#define STG 324  // 648B row stride
__global__ __launch_bounds__(128, 2) void k_mm12_mfma(
    const unsigned short* __restrict__ xb, const uint4* __restrict__ W1f,
    const uint4* __restrict__ W2f, const float* __restrict__ b1pad,
    unsigned short* __restrict__ ga2b) {
  __shared__ unsigned short stage[2 * 32 * STG];  // 41.5 KB
  int tid = threadIdx.x;
  int lane = tid & 63, wv = tid >> 6, lr = lane & 15, g = lane >> 4;
  int n0 = blockIdx.x * 64 + wv * 32;
  unsigned short* ost = stage + wv * 32 * STG;

  // ---- mm1: two 10-j halves, two node sub-tiles ----
  bf16x8 a1[2][4];
#pragma unroll
  for (int t = 0; t < 2; t++)
#pragma unroll
    for (int s = 0; s < 4; s++)
      a1[t][s] = *(const bf16x8*)(xb + (size_t)(n0 + t * 16 + lr) * 128 + s * 32 + g * 8);
#pragma unroll
  for (int half = 0; half < 2; half++) {
    f32x4 acc[2][10];
#pragma unroll
    for (int t = 0; t < 2; t++)
#pragma unroll
      for (int j = 0; j < 10; j++) acc[t][j] = (f32x4){0.f, 0.f, 0.f, 0.f};
#pragma unroll
    for (int s = 0; s < 4; s++) {
      bf16x8 w[10];
#pragma unroll
      for (int j = 0; j < 10; j++)
        w[j] = *(const bf16x8*)&W1f[(s * 20 + half * 10 + j) * 64 + lane];
      __builtin_amdgcn_sched_barrier(0);  // all 10 loads before any mfma
#pragma unroll
      for (int j = 0; j < 10; j++) {
        acc[0][j] = __builtin_amdgcn_mfma_f32_16x16x32_bf16(w[j], a1[0][s], acc[0][j], 0, 0, 0);
        acc[1][j] = __builtin_amdgcn_mfma_f32_16x16x32_bf16(w[j], a1[1][s], acc[1][j], 0, 0, 0);
      }
    }
#pragma unroll
    for (int t = 0; t < 2; t++)
#pragma unroll
      for (int j = 0; j < 10; j++) {
        int c = half * 160 + j * 16 + g * 4;
        float4 bv = *(const float4*)(b1pad + c);
        unsigned lo = f2bf(fmaxf(acc[t][j][0] + bv.x, 0.f)) |
                      (f2bf(fmaxf(acc[t][j][1] + bv.y, 0.f)) << 16);
        unsigned hi = f2bf(fmaxf(acc[t][j][2] + bv.z, 0.f)) |
                      (f2bf(fmaxf(acc[t][j][3] + bv.w, 0.f)) << 16);
        uint2 pk; pk.x = lo; pk.y = hi;
        *(uint2*)(ost + (t * 16 + lr) * STG + c) = pk;
      }
  }

  // ---- mm2: chunk0 j 0-6, chunk1 j 7-12; outputs held packed in regs ----
  uint2 pk0[2][7], pk1[2][6];
  {
    f32x4 acc[2][7];
#pragma unroll
    for (int t = 0; t < 2; t++)
#pragma unroll
      for (int j = 0; j < 7; j++) acc[t][j] = (f32x4){0.f, 0.f, 0.f, 0.f};
#pragma unroll
    for (int s = 0; s < 10; s++) {
      bf16x8 a0 = *(const bf16x8*)(ost + lr * STG + s * 32 + g * 8);
      bf16x8 a1v = *(const bf16x8*)(ost + (16 + lr) * STG + s * 32 + g * 8);
      bf16x8 w[7];
#pragma unroll
      for (int j = 0; j < 7; j++) w[j] = *(const bf16x8*)&W2f[(s * 13 + j) * 64 + lane];
      __builtin_amdgcn_sched_barrier(0);
#pragma unroll
      for (int j = 0; j < 7; j++) {
        acc[0][j] = __builtin_amdgcn_mfma_f32_16x16x32_bf16(w[j], a0, acc[0][j], 0, 0, 0);
        acc[1][j] = __builtin_amdgcn_mfma_f32_16x16x32_bf16(w[j], a1v, acc[1][j], 0, 0, 0);
      }
    }
#pragma unroll
    for (int t = 0; t < 2; t++)
#pragma unroll
      for (int j = 0; j < 7; j++) {
        pk0[t][j].x = f2bf(acc[t][j][0]) | (f2bf(acc[t][j][1]) << 16);
        pk0[t][j].y = f2bf(acc[t][j][2]) | (f2bf(acc[t][j][3]) << 16);
      }
  }
  {
    f32x4 acc[2][6];
#pragma unroll
    for (int t = 0; t < 2; t++)
#pragma unroll
      for (int j = 0; j < 6; j++) acc[t][j] = (f32x4){0.f, 0.f, 0.f, 0.f};
#pragma unroll
    for (int s = 0; s < 10; s++) {
      bf16x8 a0 = *(const bf16x8*)(ost + lr * STG + s * 32 + g * 8);
      bf16x8 a1v = *(const bf16x8*)(ost + (16 + lr) * STG + s * 32 + g * 8);
      bf16x8 w[6];
#pragma unroll
      for (int j = 0; j < 6; j++) w[j] = *(const bf16x8*)&W2f[(s * 13 + 7 + j) * 64 + lane];
      __builtin_amdgcn_sched_barrier(0);
#pragma unroll
      for (int j = 0; j < 6; j++) {
        acc[0][j] = __builtin_amdgcn_mfma_f32_16x16x32_bf16(w[j], a0, acc[0][j], 0, 0, 0);
        acc[1][j] = __builtin_amdgcn_mfma_f32_16x16x32_bf16(w[j], a1v, acc[1][j], 0, 0, 0);
      }
    }
#pragma unroll
    for (int t = 0; t < 2; t++)
#pragma unroll
      for (int j = 0; j < 6; j++) {
        pk1[t][j].x = f2bf(acc[t][j][0]) | (f2bf(acc[t][j][1]) << 16);
        pk1[t][j].y = f2bf(acc[t][j][2]) | (f2bf(acc[t][j][3]) << 16);
      }
  }
  // out epilogue: all h1 stage reads done; reuse stage as [32][216]
#pragma unroll
  for (int t = 0; t < 2; t++) {
#pragma unroll
    for (int j = 0; j < 7; j++)
      *(uint2*)(ost + (t * 16 + lr) * 216 + j * 16 + g * 4) = pk0[t][j];
#pragma unroll
    for (int j = 0; j < 6; j++)
      *(uint2*)(ost + (t * 16 + lr) * 216 + (7 + j) * 16 + g * 4) = pk1[t][j];
  }
  // wave tile rows n0..n0+31 x 208 cols = 13312 contiguous bytes
  uint4* gdst = (uint4*)(ga2b + (size_t)n0 * 208);
  for (int idx = lane; idx < 832; idx += 64) {
    int row = idx / 26, q = idx - row * 26;
    gdst[idx] = *(const uint4*)(ost + row * 216 + q * 8);
  }
}

// ---------------- launch ----------------
extern "C" void kernel_launch(void* const* d_in, const int* in_sizes, int n_in,
                              void* d_out, int out_size, void* d_ws, size_t ws_size,
                              hipStream_t stream) {
  const float* x  = (const float*)d_in[0];
  const int*   ei = (const int*)d_in[1];
  const float* W1 = (const float*)d_in[2];  // [2][58][300]
  const float* b1 = (const float*)d_in[3];
  const float* W2 = (const float*)d_in[4];  // [2][300][100]
  const float* b2 = (const float*)d_in[5];
  const float* W3 = (const float*)d_in[6];  // [2][100][1]
  const float* b3 = (const float*)d_in[7];
  float* out = (float*)d_out;

  const int N = in_sizes[0] / 58;            // 100000
  const int E = in_sizes[1] / 2;             // 800000
  const int NR = (N + 127) & ~127;           // 100096 (multiple of 64)
  const int NB = (N + 1023) / 1024;
  const int* src = ei;
  const int* dst = ei + E;

  char* ws = (char*)d_ws;
  size_t off = 0;
  auto alloc = [&](size_t bytes) -> void* {
    void* p = ws + off;
    off += (bytes + 255) & ~(size_t)255;
    return p;
  };
  unsigned* deg      = (unsigned*)alloc((size_t)2 * N * 4);
  unsigned* cnt      = deg + N;
  float*    dinv     = (float*)alloc((size_t)N * 4);
  unsigned* rowstart = (unsigned*)alloc((size_t)(N + 1) * 4);
  unsigned* rank     = (unsigned*)alloc((size_t)E * 4);
  unsigned* btot     = (unsigned*)alloc((size_t)256 * 4);
  int2*     er       = (int2*)alloc((size_t)E * 8);
  unsigned short* xb   = (unsigned short*)alloc((size_t)NR * 128 * 2);
  uint4*    W1f      = (uint4*)alloc((size_t)4 * 20 * 64 * 16);   // 80 KB
  uint4*    W2f      = (uint4*)alloc((size_t)10 * 13 * 64 * 16);  // 133 KB
  float*    b1pad    = (float*)alloc((size_t)320 * 4);
  unsigned short* ga2b = (unsigned short*)alloc((size_t)NR * 208 * 2);
  float* a3 = (float*)alloc((size_t)N * 4);
  float* g3 = (float*)alloc((size_t)N * 4);

  const int EB = (E + 255) / 256;            // 3125 edge blocks
  const int XB = ((size_t)N * 64 + 255) / 256;  // 25000 xb blocks

  // --- CSR count + ALL preps fused (preps ride under the atomic floor) ---
  hipMemsetAsync(deg, 0, (size_t)2 * N * 4, stream);
  k_count_prep<<<EB + XB + 20 + 33 + 2, 256, 0, stream>>>(
      src, dst, deg, cnt, rank, E, EB, x, xb, N, XB, W1, W1f, W2, W2f, b1, b1pad);
  k_dinv<<<(N + 255) / 256, 256, 0, stream>>>(deg, dinv, N);
  k_scan1<<<NB, 256, 0, stream>>>(cnt, btot, N);
  k_scan2<<<1, 256, 0, stream>>>(btot, rowstart, NB, N, E);
  k_scan3<<<NB, 256, 0, stream>>>(cnt, btot, rowstart, N);
  k_fill<<<(E + 255) / 256, 256, 0, stream>>>(src, dst, dinv, rowstart, rank, er, E);

  // --- layer 1+2 fused ---
  k_gather58<<<((N + 1) / 2 * 64 + 255) / 256, 256, 0, stream>>>(rowstart, er, dinv, xb, N);
  k_mm12_mfma<<<NR / 64, 128, 0, stream>>>(xb, W1f, W2f, b1pad, ga2b);
  k_gather_l2<<<(N + 3) / 4, 256, 0, stream>>>(rowstart, er, dinv, ga2b,
                                               b2, W3, W3 + 100, b3, a3, g3, N);

  // --- layer 3 ---
  k_gather1<<<(N + 255) / 256, 256, 0, stream>>>(rowstart, er, dinv, g3, a3, out, N);
}